// Round 1
// baseline (320.055 us; speedup 1.0000x reference)
//
#include <hip/hip_runtime.h>
#include <stdint.h>

// Problem constants
#define T_SEQ 2048
#define BATCH 2
#define DIM   1024
#define NH    16
#define HD    64
#define TKP   2112   // padded key rows: keys 0..2047, prefix at 2048, zeros 2049..2111

typedef _Float16 v8h __attribute__((ext_vector_type(8)));
typedef _Float16 v4h __attribute__((ext_vector_type(4)));
typedef float    f32x4 __attribute__((ext_vector_type(4)));

// async global->LDS, 16B per lane; LDS dst must be wave-uniform base (lane*16 auto)
__device__ __forceinline__ void gload16(const _Float16* g, _Float16* l) {
  __builtin_amdgcn_global_load_lds(
      (__attribute__((address_space(1))) unsigned int*)g,
      (__attribute__((address_space(3))) unsigned int*)l, 16, 0, 0);
}

// ---------------- fused f32 -> f16 convert (q,k,v,wq,wk,wv,wo in one launch) ------
__global__ void cvt_all(const float4* __restrict__ s0, const float4* __restrict__ s1,
                        const float4* __restrict__ s2, const float4* __restrict__ s3,
                        const float4* __restrict__ s4, const float4* __restrict__ s5,
                        const float4* __restrict__ s6,
                        v4h* __restrict__ d0, v4h* __restrict__ d1, v4h* __restrict__ d2,
                        v4h* __restrict__ d3, v4h* __restrict__ d4, v4h* __restrict__ d5,
                        v4h* __restrict__ d6) {
  const int NTB4 = 1048576, DD4 = 262144;      // float4 counts
  int i = blockIdx.x * 256 + threadIdx.x;      // 0..4194303
  const float4* s; v4h* d; int off;
  if (i < 3 * NTB4) {
    int t = i / NTB4; off = i - t * NTB4;
    s = t == 0 ? s0 : t == 1 ? s1 : s2;
    d = t == 0 ? d0 : t == 1 ? d1 : d2;
  } else {
    int j = i - 3 * NTB4;
    int t = j / DD4; off = j - t * DD4;
    s = t == 0 ? s3 : t == 1 ? s4 : t == 2 ? s5 : s6;
    d = t == 0 ? d3 : t == 1 ? d4 : t == 2 ? d5 : d6;
  }
  float4 v = s[off];
  v4h o = { (_Float16)v.x, (_Float16)v.y, (_Float16)v.z, (_Float16)v.w };
  d[off] = o;
}

// ---------------- prefix MLP (fp32, tiny) ----------------
__global__ void prefix_h_k(const float* __restrict__ wte, const float* __restrict__ w1,
                           const float* __restrict__ b1, const int* __restrict__ lang,
                           float* __restrict__ hbuf) {
  int wid = blockIdx.x * 4 + (threadIdx.x >> 6);   // 0..1599 = b*800+j
  int lane = threadIdx.x & 63;
  int b = wid / 800, j = wid - b * 800;
  int c = lang[b];
  const float* wr = w1 + ((size_t)c * 800 + j) * 1024;
  const float* em = wte + (size_t)c * 1024;
  float s = 0.f;
  for (int d = lane; d < 1024; d += 64) s += wr[d] * em[d];
  for (int off = 32; off > 0; off >>= 1) s += __shfl_down(s, off, 64);
  if (lane == 0) hbuf[wid] = tanhf(s + b1[c * 800 + j]);
}

// kv[b,e]: e<1024 -> prefix K (key slot 2048), else prefix V (col slot 2048)
__global__ void prefix_kv_k(const float* __restrict__ w2, const float* __restrict__ b2,
                            const float* __restrict__ hbuf, const int* __restrict__ lang,
                            _Float16* __restrict__ kb, _Float16* __restrict__ vb) {
  int wid = blockIdx.x * 4 + (threadIdx.x >> 6);   // 0..4095 = b*2048+e
  int lane = threadIdx.x & 63;
  int b = wid >> 11, e = wid & 2047;
  int c = lang[b];
  const float* wr = w2 + ((size_t)c * 2048 + e) * 800;
  const float* hb = hbuf + b * 800;
  float s = 0.f;
  for (int j = lane; j < 800; j += 64) s += wr[j] * hb[j];
  for (int off = 32; off > 0; off >>= 1) s += __shfl_down(s, off, 64);
  if (lane == 0) {
    float val = s + b2[c * 2048 + e];
    if (e < 1024) {
      int h = e >> 6, hd = e & 63;
      kb[((size_t)(b * 16 + h) * TKP + 2048) * 64 + hd] = (_Float16)val;
    } else {
      int d = e - 1024;
      int h = d >> 6, hd = d & 63;
      vb[((size_t)(b * 16 + h) * 64 + hd) * TKP + 2048] = (_Float16)val;
    }
  }
}

// zero key rows 2048..2111 / V cols 2048..2111 with contiguous 16B stores.
// Runs BEFORE prefix_kv_k, which then overwrites slot 2048.
__global__ void pad_k(_Float16* kb, _Float16* vb) {
  int bh = blockIdx.x;
  v8h z = {};
  _Float16* kp = kb + ((size_t)bh * TKP + 2048) * 64;      // 64 rows x 64 = contiguous
  for (int i = threadIdx.x; i < 512; i += 256) *(v8h*)&kp[i * 8] = z;
  for (int i = threadIdx.x; i < 512; i += 256) {           // 64 hd-rows x 64 t, 8 segs each
    int c = i >> 3, seg = i & 7;
    *(v8h*)&vb[((size_t)bh * 64 + c) * TKP + 2048 + seg * 8] = z;
  }
}

// ---------------- gemm_bt: Out[r,e] = sum_d A[r,d]*W[e,d] + bias[e] ----------------
// 128x128 tile, BK=64, 4 waves 2x2, 16x16x32 f16 MFMA.
// blockIdx.x = row-tile (XCD swizzle: same rows land on same XCD), y = col-tile.
// mode 0: q (*0.125 -> [B,H,T,hd]); 1: k (-> [B,H,t,hd], prefix at 2048);
// mode 2: v transposed (-> [B,H,hd,t]); 3: fp32 out (d_out [T,B,D], direct full-line stores)
// Epilogue (modes 0-2) restages through wave-private LDS (16B-aligned strides) so
// every global store instruction writes full 64B cache lines.
__global__ __launch_bounds__(256) void gemm_bt_k(
    const _Float16* __restrict__ A0, const _Float16* __restrict__ A1, const _Float16* __restrict__ A2,
    const _Float16* __restrict__ W0, const _Float16* __restrict__ W1, const _Float16* __restrict__ W2,
    const float* __restrict__ bs0, const float* __restrict__ bs1, const float* __restrict__ bs2,
    _Float16* __restrict__ qb, _Float16* __restrict__ kb, _Float16* __restrict__ vb,
    float* __restrict__ fout, int mode_base)
{
  __shared__ __align__(16) _Float16 smem[128 * 64 * 2];    // As | Bs, reused as epilogue stage
  _Float16* As = smem;
  _Float16* Bs = smem + 128 * 64;
  const int mode = mode_base + blockIdx.z;
  const _Float16* A = (mode == 1) ? A1 : (mode == 2) ? A2 : A0;
  const _Float16* W = (mode == 1) ? W1 : (mode == 2) ? W2 : W0;
  const float* bias = (mode == 1) ? bs1 : (mode == 2) ? bs2 : bs0;
  const int tid = threadIdx.x, w = tid >> 6, lane = tid & 63;
  const int quad = lane >> 4, l15 = lane & 15;
  const int r0 = blockIdx.x * 128, c0 = blockIdx.y * 128;
  const int wm = w >> 1, wn = w & 1;
  const int srow = lane >> 3, sseg = lane & 7;
  f32x4 acc[4][4] = {};
  for (int k0 = 0; k0 < 1024; k0 += 64) {
    for (int i = 0; i < 4; ++i) {
      int rowb = w * 32 + i * 8;
      gload16(A + (size_t)(r0 + rowb + srow) * 1024 + k0 + sseg * 8, &As[rowb * 64]);
      gload16(W + (size_t)(c0 + rowb + srow) * 1024 + k0 + sseg * 8, &Bs[rowb * 64]);
    }
    __syncthreads();
    for (int ks = 0; ks < 2; ++ks) {
      v8h af[4], bfr[4];
      for (int mt = 0; mt < 4; ++mt)
        af[mt] = *(const v8h*)&As[(wm * 64 + mt * 16 + l15) * 64 + ks * 32 + quad * 8];
      for (int nt = 0; nt < 4; ++nt)
        bfr[nt] = *(const v8h*)&Bs[(wn * 64 + nt * 16 + l15) * 64 + ks * 32 + quad * 8];
      for (int mt = 0; mt < 4; ++mt)
        for (int nt = 0; nt < 4; ++nt)
          acc[mt][nt] = __builtin_amdgcn_mfma_f32_16x16x32_f16(af[mt], bfr[nt], acc[mt][nt], 0, 0, 0);
    }
    __syncthreads();
  }
  // ---- epilogue; C/D layout: col = lane&15, row = quad*4 + reg ----
  if (mode == 3) {
    // fp32 direct: 16 l15-lanes x 4B = one full 64B line per quad. Already ideal.
    for (int nt = 0; nt < 4; ++nt) {
      int e = c0 + wn * 64 + nt * 16 + l15;
      float be = bias[e];
      for (int mt = 0; mt < 4; ++mt) {
        int rb = r0 + wm * 64 + mt * 16 + quad * 4;
        for (int reg = 0; reg < 4; ++reg)
          fout[(size_t)(rb + reg) * 1024 + e] = acc[mt][nt][reg] + be;
      }
    }
    return;
  }
  _Float16* st = smem + w * 4096;                  // wave-private stage (8192 B)
  const float qscale = (mode == 0) ? 0.125f : 1.0f;
  for (int p = 0; p < 2; ++p) {                    // pass = half of the e-range (32 cols)
    __syncthreads();
    for (int ntl = 0; ntl < 2; ++ntl) {
      int nt = p * 2 + ntl;
      int e = c0 + wn * 64 + nt * 16 + l15;
      float be = bias[e];
      for (int mt = 0; mt < 4; ++mt)
        for (int reg = 0; reg < 4; ++reg) {
          float val = (acc[mt][nt][reg] + be) * qscale;
          int rl = mt * 16 + quad * 4 + reg;       // 0..63 local row
          if (mode != 2) st[rl * 40 + ntl * 16 + l15] = (_Float16)val;       // stride 40: 80B, 16B-mult
          else st[(ntl * 16 + l15) * 72 + (rl & 1) * 32 + (rl >> 1)] = (_Float16)val;  // stride 72: 144B
        }
    }
    __syncthreads();
    if (mode != 2) {
      // st[row r (64)][e (32), stride 40]; 4-lane groups write full 64B lines
      for (int it = 0; it < 4; ++it) {
        int chunk = it * 64 + lane;                // 0..255
        int rr = chunk >> 2, seg = chunk & 3;
        v8h val = *(const v8h*)&st[rr * 40 + seg * 8];
        int r = r0 + wm * 64 + rr, b = r & 1, t = r >> 1;
        int e0 = c0 + wn * 64 + p * 32 + seg * 8;
        int h = e0 >> 6, hd0 = e0 & 63;
        if (mode == 0) *(v8h*)&qb[((size_t)(b * 16 + h) * 2048 + t) * 64 + hd0] = val;
        else           *(v8h*)&kb[((size_t)(b * 16 + h) * TKP + t) * 64 + hd0] = val;
      }
    } else {
      // st[e (32), stride 72][b(2)*32 + t(32)]; 4-lane groups write full 64B lines
      for (int it = 0; it < 4; ++it) {
        int chunk = it * 64 + lane;                // 0..255
        int el = chunk >> 3, b = (chunk >> 2) & 1, qs = chunk & 3;
        v8h val = *(const v8h*)&st[el * 72 + b * 32 + qs * 8];
        int e = c0 + wn * 64 + p * 32 + el;
        int h = e >> 6, hd = e & 63;
        int t0 = ((r0 + wm * 64) >> 1) + qs * 8;
        *(v8h*)&vb[((size_t)(b * 16 + h) * 64 + hd) * TKP + t0] = val;
      }
    }
  }
}

// ---------------- flash attention (v3) ----------------
// v3 change vs v2: q-tile halved 128 -> 64 rows. Grid (32 bh, 32 q-tiles) = 1024
// blocks = 4 blocks/CU (was 512 = 2/CU, the occupancy cap: Occupancy was 17%,
// MfmaUtil 20%, VALUBusy 44% -> latency-bound, not pipe-bound). LDS drops
// 55.3KB -> 36.9KB so 4 blocks/CU fit: 16 waves/CU. Each wave now owns 16
// q-rows (1 MFMA col-tile), per-iter work halves, reg pressure drops.
// XCD swizzle preserved: linear = bh + 32*qt -> XCD = bh%8, so all q-tiles of
// one bh share that XCD's L2 (4 bh/XCD x 540KB K/V = 2.2MB < 4MB L2).
__global__ __launch_bounds__(256) void attn_k(
    const _Float16* __restrict__ qb, const _Float16* __restrict__ kb,
    const _Float16* __restrict__ vb, _Float16* __restrict__ ctx)
{
  __shared__ __align__(16) _Float16 Qs[64 * 72];
  __shared__ __align__(16) _Float16 Ks[64 * 72];
  __shared__ __align__(16) _Float16 Vs[64 * 72];
  __shared__ __align__(16) _Float16 Ps[64 * 72];
  const int bh = blockIdx.x;
  const int qt0 = blockIdx.y * 64;
  const int tid = threadIdx.x, w = tid >> 6, lane = tid & 63;
  const int quad = lane >> 4, l15 = lane & 15;
  for (int it = 0; it < 2; ++it) {
    int slot = it * 256 + tid;
    int row = slot >> 3, seg = slot & 7;
    int4 v = *(const int4*)(qb + ((size_t)bh * 2048 + qt0 + row) * 64 + seg * 8);
    *(int4*)&Qs[row * 72 + seg * 8] = v;
  }
  // staging coords: row = tid>>3 (0..31, +32 for second half), seg = tid&7
  const int sr = tid >> 3, sseg = tid & 7;
  const _Float16* kptr = kb + (size_t)bh * TKP * 64 + sr * 64 + sseg * 8;
  const _Float16* vptr = vb + (size_t)bh * 64 * TKP + (size_t)sr * TKP + sseg * 8;
  int4 kp0 = *(const int4*)kptr, kp1 = *(const int4*)(kptr + 2048);
  int4 vp0 = *(const int4*)vptr, vp1 = *(const int4*)(vptr + 32 * TKP);
  kptr += 4096; vptr += 64;
  f32x4 O[4] = {};
  float l_ = 0.f;                                  // per-lane partial (this quad's keys)
  for (int kc = 0; kc < 33; ++kc) {
    __syncthreads();                               // prior-iter Ks/Vs reads done
    *(int4*)&Ks[sr * 72 + sseg * 8] = kp0;
    *(int4*)&Ks[(sr + 32) * 72 + sseg * 8] = kp1;
    *(int4*)&Vs[sr * 72 + sseg * 8] = vp0;
    *(int4*)&Vs[(sr + 32) * 72 + sseg * 8] = vp1;
    __syncthreads();
    if (kc < 32) {                                 // prefetch next chunk; lands during compute
      kp0 = *(const int4*)kptr; kp1 = *(const int4*)(kptr + 2048);
      vp0 = *(const int4*)vptr; vp1 = *(const int4*)(vptr + 32 * TKP);
      kptr += 4096; vptr += 64;
    }
    // S^T = K(64xhd) . Q^T(hd x 16): rows=key, cols=query
    f32x4 S[4] = {};
    for (int ks = 0; ks < 2; ++ks) {
      v8h q0 = *(const v8h*)&Qs[(w * 16 + l15) * 72 + ks * 32 + quad * 8];
      for (int mt = 0; mt < 4; ++mt) {
        v8h ak = *(const v8h*)&Ks[(mt * 16 + l15) * 72 + ks * 32 + quad * 8];
        S[mt] = __builtin_amdgcn_mfma_f32_16x16x32_f16(ak, q0, S[mt], 0, 0, 0);
      }
    }
    if (kc == 32) {                      // local key 0 = prefix (valid); rest = pad
      for (int mt = 0; mt < 4; ++mt)
        for (int reg = 0; reg < 4; ++reg)
          if (mt * 16 + quad * 4 + reg > 0) S[mt][reg] = -1e30f;
    }
    // softmax-lite: P = exp(S) (no max subtraction), accumulate per-lane l
    float rsum = 0.f;
    for (int mt = 0; mt < 4; ++mt) {
      float p0 = __expf(S[mt][0]);
      float p1 = __expf(S[mt][1]);
      float p2 = __expf(S[mt][2]);
      float p3 = __expf(S[mt][3]);
      rsum += (p0 + p1) + (p2 + p3);
      v4h pk4 = { (_Float16)p0, (_Float16)p1, (_Float16)p2, (_Float16)p3 };
      *(v4h*)&Ps[(w * 16 + l15) * 72 + mt * 16 + quad * 4] = pk4;
    }
    l_ += rsum;
    // O^T += V^T(hd x 64) . P^T(64 x 16); Ps rows are wave-private, no barrier needed
    for (int ks = 0; ks < 2; ++ks) {
      v8h p0 = *(const v8h*)&Ps[(w * 16 + l15) * 72 + ks * 32 + quad * 8];
      for (int ht = 0; ht < 4; ++ht) {
        v8h av = *(const v8h*)&Vs[(ht * 16 + l15) * 72 + ks * 32 + quad * 8];
        O[ht] = __builtin_amdgcn_mfma_f32_16x16x32_f16(av, p0, O[ht], 0, 0, 0);
      }
    }
  }
  // reduce l across the 4 quads (each lane's partial covers its quad's key rows)
  l_ += __shfl_xor(l_, 16, 64);
  l_ += __shfl_xor(l_, 32, 64);
  const int b = bh >> 4, hh = bh & 15;
  float inv = 1.f / l_;
  int q = qt0 + w * 16 + l15;
  for (int ht = 0; ht < 4; ++ht) {
    v4h o4 = { (_Float16)(O[ht][0] * inv), (_Float16)(O[ht][1] * inv),
               (_Float16)(O[ht][2] * inv), (_Float16)(O[ht][3] * inv) };
    *(v4h*)(ctx + ((size_t)q * 2 + b) * 1024 + hh * 64 + ht * 16 + quad * 4) = o4;
  }
}

extern "C" void kernel_launch(void* const* d_in, const int* in_sizes, int n_in,
                              void* d_out, int out_size, void* d_ws, size_t ws_size,
                              hipStream_t stream) {
  (void)in_sizes; (void)n_in; (void)out_size; (void)ws_size;
  const float* query = (const float*)d_in[0];
  const float* key_  = (const float*)d_in[1];
  const float* value = (const float*)d_in[2];
  const float* wq = (const float*)d_in[3];
  const float* bq = (const float*)d_in[4];
  const float* wk = (const float*)d_in[5];
  const float* bk = (const float*)d_in[6];
  const float* wv = (const float*)d_in[7];
  const float* bv = (const float*)d_in[8];
  const float* wo = (const float*)d_in[9];
  const float* bo = (const float*)d_in[10];
  const float* wte = (const float*)d_in[11];
  const float* w1 = (const float*)d_in[12];
  const float* b1 = (const float*)d_in[13];
  const float* w2 = (const float*)d_in[14];
  const float* b2 = (const float*)d_in[15];
  const int* lang = (const int*)d_in[16];
  float* out = (float*)d_out;

  const size_t NTB = (size_t)T_SEQ * BATCH * DIM;   // 4194304
  const size_t DD  = (size_t)DIM * DIM;             // 1048576
  const size_t KVN = (size_t)BATCH * NH * TKP * HD; // 4325376
  _Float16* xq  = (_Float16*)d_ws;
  _Float16* xk  = xq + NTB;
  _Float16* xv  = xk + NTB;
  _Float16* wqb = xv + NTB;
  _Float16* wkb = wqb + DD;
  _Float16* wvb = wkb + DD;
  _Float16* wob = wvb + DD;
  _Float16* qbuf = wob + DD;
  _Float16* kbuf = qbuf + NTB;
  _Float16* vbuf = kbuf + KVN;
  float* hbuf = (float*)(vbuf + KVN);
  _Float16* ctxb = xq;   // alias: xq is dead after the QKV projections

  cvt_all<<<16384, 256, 0, stream>>>((const float4*)query, (const float4*)key_,
                                     (const float4*)value, (const float4*)wq,
                                     (const float4*)wk, (const float4*)wv, (const float4*)wo,
                                     (v4h*)xq, (v4h*)xk, (v4h*)xv, (v4h*)wqb,
                                     (v4h*)wkb, (v4h*)wvb, (v4h*)wob);
  pad_k<<<32, 256, 0, stream>>>(kbuf, vbuf);
  prefix_h_k<<<400, 256, 0, stream>>>(wte, w1, b1, lang, hbuf);
  prefix_kv_k<<<1024, 256, 0, stream>>>(w2, b2, hbuf, lang, kbuf, vbuf);
  gemm_bt_k<<<dim3(32, 8, 3), 256, 0, stream>>>(xq, xk, xv, wqb, wkb, wvb, bq, bk, bv,
                                                qbuf, kbuf, vbuf, nullptr, 0);
  attn_k<<<dim3(32, 32), 256, 0, stream>>>(qbuf, kbuf, vbuf, ctxb);
  gemm_bt_k<<<dim3(32, 8, 1), 256, 0, stream>>>(ctxb, ctxb, ctxb, wob, wob, wob, bo, bo, bo,
                                                qbuf, kbuf, vbuf, out, 3);
}

// Round 2
// 307.502 us; speedup vs baseline: 1.0408x; 1.0408x over previous
//
#include <hip/hip_runtime.h>
#include <stdint.h>

// Problem constants
#define T_SEQ 2048
#define BATCH 2
#define DIM   1024
#define NH    16
#define HD    64
#define TKP   2112   // padded key rows: keys 0..2047, prefix at 2048, zeros 2049..2111

typedef _Float16 v8h __attribute__((ext_vector_type(8)));
typedef _Float16 v4h __attribute__((ext_vector_type(4)));
typedef float    f32x4 __attribute__((ext_vector_type(4)));

// async global->LDS, 16B per lane; LDS dst must be wave-uniform base (lane*16 auto)
__device__ __forceinline__ void gload16(const _Float16* g, _Float16* l) {
  __builtin_amdgcn_global_load_lds(
      (__attribute__((address_space(1))) unsigned int*)g,
      (__attribute__((address_space(3))) unsigned int*)l, 16, 0, 0);
}

// ---------------- fused f32 -> f16 convert (q,k,v,wq,wk,wv,wo in one launch) ------
__global__ void cvt_all(const float4* __restrict__ s0, const float4* __restrict__ s1,
                        const float4* __restrict__ s2, const float4* __restrict__ s3,
                        const float4* __restrict__ s4, const float4* __restrict__ s5,
                        const float4* __restrict__ s6,
                        v4h* __restrict__ d0, v4h* __restrict__ d1, v4h* __restrict__ d2,
                        v4h* __restrict__ d3, v4h* __restrict__ d4, v4h* __restrict__ d5,
                        v4h* __restrict__ d6) {
  const int NTB4 = 1048576, DD4 = 262144;      // float4 counts
  int i = blockIdx.x * 256 + threadIdx.x;      // 0..4194303
  const float4* s; v4h* d; int off;
  if (i < 3 * NTB4) {
    int t = i / NTB4; off = i - t * NTB4;
    s = t == 0 ? s0 : t == 1 ? s1 : s2;
    d = t == 0 ? d0 : t == 1 ? d1 : d2;
  } else {
    int j = i - 3 * NTB4;
    int t = j / DD4; off = j - t * DD4;
    s = t == 0 ? s3 : t == 1 ? s4 : t == 2 ? s5 : s6;
    d = t == 0 ? d3 : t == 1 ? d4 : t == 2 ? d5 : d6;
  }
  float4 v = s[off];
  v4h o = { (_Float16)v.x, (_Float16)v.y, (_Float16)v.z, (_Float16)v.w };
  d[off] = o;
}

// ---------------- prefix MLP (fp32, tiny) ----------------
__global__ void prefix_h_k(const float* __restrict__ wte, const float* __restrict__ w1,
                           const float* __restrict__ b1, const int* __restrict__ lang,
                           float* __restrict__ hbuf) {
  int wid = blockIdx.x * 4 + (threadIdx.x >> 6);   // 0..1599 = b*800+j
  int lane = threadIdx.x & 63;
  int b = wid / 800, j = wid - b * 800;
  int c = lang[b];
  const float* wr = w1 + ((size_t)c * 800 + j) * 1024;
  const float* em = wte + (size_t)c * 1024;
  float s = 0.f;
  for (int d = lane; d < 1024; d += 64) s += wr[d] * em[d];
  for (int off = 32; off > 0; off >>= 1) s += __shfl_down(s, off, 64);
  if (lane == 0) hbuf[wid] = tanhf(s + b1[c * 800 + j]);
}

// kv[b,e]: e<1024 -> prefix K (key slot 2048), else prefix V (col slot 2048)
__global__ void prefix_kv_k(const float* __restrict__ w2, const float* __restrict__ b2,
                            const float* __restrict__ hbuf, const int* __restrict__ lang,
                            _Float16* __restrict__ kb, _Float16* __restrict__ vb) {
  int wid = blockIdx.x * 4 + (threadIdx.x >> 6);   // 0..4095 = b*2048+e
  int lane = threadIdx.x & 63;
  int b = wid >> 11, e = wid & 2047;
  int c = lang[b];
  const float* wr = w2 + ((size_t)c * 2048 + e) * 800;
  const float* hb = hbuf + b * 800;
  float s = 0.f;
  for (int j = lane; j < 800; j += 64) s += wr[j] * hb[j];
  for (int off = 32; off > 0; off >>= 1) s += __shfl_down(s, off, 64);
  if (lane == 0) {
    float val = s + b2[c * 2048 + e];
    if (e < 1024) {
      int h = e >> 6, hd = e & 63;
      kb[((size_t)(b * 16 + h) * TKP + 2048) * 64 + hd] = (_Float16)val;
    } else {
      int d = e - 1024;
      int h = d >> 6, hd = d & 63;
      vb[((size_t)(b * 16 + h) * 64 + hd) * TKP + 2048] = (_Float16)val;
    }
  }
}

// zero key rows 2048..2111 / V cols 2048..2111 with contiguous 16B stores.
// Runs BEFORE prefix_kv_k, which then overwrites slot 2048.
__global__ void pad_k(_Float16* kb, _Float16* vb) {
  int bh = blockIdx.x;
  v8h z = {};
  _Float16* kp = kb + ((size_t)bh * TKP + 2048) * 64;      // 64 rows x 64 = contiguous
  for (int i = threadIdx.x; i < 512; i += 256) *(v8h*)&kp[i * 8] = z;
  for (int i = threadIdx.x; i < 512; i += 256) {           // 64 hd-rows x 64 t, 8 segs each
    int c = i >> 3, seg = i & 7;
    *(v8h*)&vb[((size_t)bh * 64 + c) * TKP + 2048 + seg * 8] = z;
  }
}

// ---------------- gemm_bt: Out[r,e] = sum_d A[r,d]*W[e,d] + bias[e] ----------------
// 128x128 tile, BK=64, 4 waves 2x2, 16x16x32 f16 MFMA.
// blockIdx.x = row-tile (XCD swizzle: same rows land on same XCD), y = col-tile.
// mode 0: q (*0.125*log2e -> [B,H,T,hd]); 1: k (-> [B,H,t,hd], prefix at 2048);
// mode 2: v transposed (-> [B,H,hd,t]); 3: fp32 out (d_out [T,B,D], direct full-line stores)
// Epilogue (modes 0-2) restages through wave-private LDS (16B-aligned strides) so
// every global store instruction writes full 64B cache lines.
__global__ __launch_bounds__(256) void gemm_bt_k(
    const _Float16* __restrict__ A0, const _Float16* __restrict__ A1, const _Float16* __restrict__ A2,
    const _Float16* __restrict__ W0, const _Float16* __restrict__ W1, const _Float16* __restrict__ W2,
    const float* __restrict__ bs0, const float* __restrict__ bs1, const float* __restrict__ bs2,
    _Float16* __restrict__ qb, _Float16* __restrict__ kb, _Float16* __restrict__ vb,
    float* __restrict__ fout, int mode_base)
{
  __shared__ __align__(16) _Float16 smem[128 * 64 * 2];    // As | Bs, reused as epilogue stage
  _Float16* As = smem;
  _Float16* Bs = smem + 128 * 64;
  const int mode = mode_base + blockIdx.z;
  const _Float16* A = (mode == 1) ? A1 : (mode == 2) ? A2 : A0;
  const _Float16* W = (mode == 1) ? W1 : (mode == 2) ? W2 : W0;
  const float* bias = (mode == 1) ? bs1 : (mode == 2) ? bs2 : bs0;
  const int tid = threadIdx.x, w = tid >> 6, lane = tid & 63;
  const int quad = lane >> 4, l15 = lane & 15;
  const int r0 = blockIdx.x * 128, c0 = blockIdx.y * 128;
  const int wm = w >> 1, wn = w & 1;
  const int srow = lane >> 3, sseg = lane & 7;
  f32x4 acc[4][4] = {};
  for (int k0 = 0; k0 < 1024; k0 += 64) {
    for (int i = 0; i < 4; ++i) {
      int rowb = w * 32 + i * 8;
      gload16(A + (size_t)(r0 + rowb + srow) * 1024 + k0 + sseg * 8, &As[rowb * 64]);
      gload16(W + (size_t)(c0 + rowb + srow) * 1024 + k0 + sseg * 8, &Bs[rowb * 64]);
    }
    __syncthreads();
    for (int ks = 0; ks < 2; ++ks) {
      v8h af[4], bfr[4];
      for (int mt = 0; mt < 4; ++mt)
        af[mt] = *(const v8h*)&As[(wm * 64 + mt * 16 + l15) * 64 + ks * 32 + quad * 8];
      for (int nt = 0; nt < 4; ++nt)
        bfr[nt] = *(const v8h*)&Bs[(wn * 64 + nt * 16 + l15) * 64 + ks * 32 + quad * 8];
      for (int mt = 0; mt < 4; ++mt)
        for (int nt = 0; nt < 4; ++nt)
          acc[mt][nt] = __builtin_amdgcn_mfma_f32_16x16x32_f16(af[mt], bfr[nt], acc[mt][nt], 0, 0, 0);
    }
    __syncthreads();
  }
  // ---- epilogue; C/D layout: col = lane&15, row = quad*4 + reg ----
  if (mode == 3) {
    // fp32 direct: 16 l15-lanes x 4B = one full 64B line per quad. Already ideal.
    for (int nt = 0; nt < 4; ++nt) {
      int e = c0 + wn * 64 + nt * 16 + l15;
      float be = bias[e];
      for (int mt = 0; mt < 4; ++mt) {
        int rb = r0 + wm * 64 + mt * 16 + quad * 4;
        for (int reg = 0; reg < 4; ++reg)
          fout[(size_t)(rb + reg) * 1024 + e] = acc[mt][nt][reg] + be;
      }
    }
    return;
  }
  _Float16* st = smem + w * 4096;                  // wave-private stage (8192 B)
  // mode 0: fold softmax's log2(e) into the Q scale so attn can use raw v_exp_f32
  const float qscale = (mode == 0) ? 0.125f * 1.44269504088896341f : 1.0f;
  for (int p = 0; p < 2; ++p) {                    // pass = half of the e-range (32 cols)
    __syncthreads();
    for (int ntl = 0; ntl < 2; ++ntl) {
      int nt = p * 2 + ntl;
      int e = c0 + wn * 64 + nt * 16 + l15;
      float be = bias[e];
      for (int mt = 0; mt < 4; ++mt)
        for (int reg = 0; reg < 4; ++reg) {
          float val = (acc[mt][nt][reg] + be) * qscale;
          int rl = mt * 16 + quad * 4 + reg;       // 0..63 local row
          if (mode != 2) st[rl * 40 + ntl * 16 + l15] = (_Float16)val;       // stride 40: 80B, 16B-mult
          else st[(ntl * 16 + l15) * 72 + (rl & 1) * 32 + (rl >> 1)] = (_Float16)val;  // stride 72: 144B
        }
    }
    __syncthreads();
    if (mode != 2) {
      // st[row r (64)][e (32), stride 40]; 4-lane groups write full 64B lines
      for (int it = 0; it < 4; ++it) {
        int chunk = it * 64 + lane;                // 0..255
        int rr = chunk >> 2, seg = chunk & 3;
        v8h val = *(const v8h*)&st[rr * 40 + seg * 8];
        int r = r0 + wm * 64 + rr, b = r & 1, t = r >> 1;
        int e0 = c0 + wn * 64 + p * 32 + seg * 8;
        int h = e0 >> 6, hd0 = e0 & 63;
        if (mode == 0) *(v8h*)&qb[((size_t)(b * 16 + h) * 2048 + t) * 64 + hd0] = val;
        else           *(v8h*)&kb[((size_t)(b * 16 + h) * TKP + t) * 64 + hd0] = val;
      }
    } else {
      // st[e (32), stride 72][b(2)*32 + t(32)]; 4-lane groups write full 64B lines
      for (int it = 0; it < 4; ++it) {
        int chunk = it * 64 + lane;                // 0..255
        int el = chunk >> 3, b = (chunk >> 2) & 1, qs = chunk & 3;
        v8h val = *(const v8h*)&st[el * 72 + b * 32 + qs * 8];
        int e = c0 + wn * 64 + p * 32 + el;
        int h = e >> 6, hd = e & 63;
        int t0 = ((r0 + wm * 64) >> 1) + qs * 8;
        *(v8h*)&vb[((size_t)(b * 16 + h) * 64 + hd) * TKP + t0] = val;
      }
    }
  }
}

// ---------------- flash attention (v4) ----------------
// Post-mortem of v3 (64-row tile): occupancy rose 17->30% but dur 68->80us and
// bank conflicts +50% -- halving the q-tile DOUBLED total K/V staging + K/V LDS
// reads (every block walks all 2112 keys). K/V amortization >> occupancy here.
// v4: back to 128-row q-tile (grid 32x16), and attack per-iter overhead instead:
//  - Q fragments in REGISTERS (loop-invariant, 4x v8h/wave) -- Qs LDS gone.
//  - double-buffered Ks/Vs -> ONE __syncthreads per iter (was 2). Write chunk
//    kc into buf kc&1 pre-barrier, compute post-barrier; parity makes it safe.
//  - softmax denominator via MFMA: l = mfma(ones, P) accumulates column sums
//    (replaces 32 VALU adds/iter + end shuffle-reduce; every lane has l in reg0).
//  - exp(S) = single v_exp_f32: log2(e) folded into Q projection scale.
__global__ __launch_bounds__(256) void attn_k(
    const _Float16* __restrict__ qb, const _Float16* __restrict__ kb,
    const _Float16* __restrict__ vb, _Float16* __restrict__ ctx)
{
  __shared__ __align__(16) _Float16 Ks[2][64 * 72];
  __shared__ __align__(16) _Float16 Vs[2][64 * 72];
  __shared__ __align__(16) _Float16 Ps[128 * 72];
  const int bh = blockIdx.x;
  const int qt0 = blockIdx.y * 128;
  const int tid = threadIdx.x, w = tid >> 6, lane = tid & 63;
  const int quad = lane >> 4, l15 = lane & 15;
  // loop-invariant Q fragments (B-operand): row = w*32 + nt*16 + l15, k = ks*32+quad*8
  v8h qf[2][2];
  for (int nt = 0; nt < 2; ++nt)
    for (int ks = 0; ks < 2; ++ks)
      qf[nt][ks] = *(const v8h*)(qb + ((size_t)bh * 2048 + qt0 + w * 32 + nt * 16 + l15) * 64
                                 + ks * 32 + quad * 8);
  // staging coords: row = tid>>3 (0..31, +32 for second half), seg = tid&7
  const int sr = tid >> 3, sseg = tid & 7;
  const _Float16* kptr = kb + (size_t)bh * TKP * 64 + sr * 64 + sseg * 8;
  const _Float16* vptr = vb + (size_t)bh * 64 * TKP + (size_t)sr * TKP + sseg * 8;
  int4 kp0 = *(const int4*)kptr, kp1 = *(const int4*)(kptr + 2048);
  int4 vp0 = *(const int4*)vptr, vp1 = *(const int4*)(vptr + 32 * TKP);
  kptr += 4096; vptr += 64;
  f32x4 O[4][2] = {};
  f32x4 lacc[2] = {};
  const v8h vones = { (_Float16)1.f, (_Float16)1.f, (_Float16)1.f, (_Float16)1.f,
                      (_Float16)1.f, (_Float16)1.f, (_Float16)1.f, (_Float16)1.f };
  for (int kc = 0; kc < 33; ++kc) {
    _Float16* Kb = Ks[kc & 1];
    _Float16* Vb = Vs[kc & 1];
    // write chunk kc (in regs) to this iter's buffer; other waves may still be
    // computing iter kc-1 on the OTHER buffer -- parity keeps this race-free.
    *(int4*)&Kb[sr * 72 + sseg * 8] = kp0;
    *(int4*)&Kb[(sr + 32) * 72 + sseg * 8] = kp1;
    *(int4*)&Vb[sr * 72 + sseg * 8] = vp0;
    *(int4*)&Vb[(sr + 32) * 72 + sseg * 8] = vp1;
    __syncthreads();
    if (kc < 32) {                                 // prefetch next chunk; lands during compute
      kp0 = *(const int4*)kptr; kp1 = *(const int4*)(kptr + 2048);
      vp0 = *(const int4*)vptr; vp1 = *(const int4*)(vptr + 32 * TKP);
      kptr += 4096; vptr += 64;
    }
    // S^T = K(64xhd) . Q^T(hd x 32): rows=key, cols=query
    f32x4 S[4][2] = {};
    for (int ks = 0; ks < 2; ++ks) {
      for (int mt = 0; mt < 4; ++mt) {
        v8h ak = *(const v8h*)&Kb[(mt * 16 + l15) * 72 + ks * 32 + quad * 8];
        S[mt][0] = __builtin_amdgcn_mfma_f32_16x16x32_f16(ak, qf[0][ks], S[mt][0], 0, 0, 0);
        S[mt][1] = __builtin_amdgcn_mfma_f32_16x16x32_f16(ak, qf[1][ks], S[mt][1], 0, 0, 0);
      }
    }
    if (kc == 32) {                      // local key 0 = prefix (valid); rest = pad
      for (int mt = 0; mt < 4; ++mt)
        for (int reg = 0; reg < 4; ++reg)
          if (mt * 16 + quad * 4 + reg > 0) { S[mt][0][reg] = -1e30f; S[mt][1][reg] = -1e30f; }
    }
    // softmax-lite: P = exp2(S) (S pre-scaled by log2e at projection); no VALU sum
    for (int nt = 0; nt < 2; ++nt)
      for (int mt = 0; mt < 4; ++mt) {
        v4h pk4 = { (_Float16)__builtin_amdgcn_exp2f(S[mt][nt][0]),
                    (_Float16)__builtin_amdgcn_exp2f(S[mt][nt][1]),
                    (_Float16)__builtin_amdgcn_exp2f(S[mt][nt][2]),
                    (_Float16)__builtin_amdgcn_exp2f(S[mt][nt][3]) };
        *(v4h*)&Ps[(w * 32 + nt * 16 + l15) * 72 + mt * 16 + quad * 4] = pk4;
      }
    // O^T += V^T(hd x 64) . P^T(64 x 32); Ps rows are wave-private, no barrier needed.
    // l += Ones(16x64) . P^T via MFMA: every output row = column sum of P.
    for (int ks = 0; ks < 2; ++ks) {
      v8h p0 = *(const v8h*)&Ps[(w * 32 + l15) * 72 + ks * 32 + quad * 8];
      v8h p1 = *(const v8h*)&Ps[(w * 32 + 16 + l15) * 72 + ks * 32 + quad * 8];
      for (int ht = 0; ht < 4; ++ht) {
        v8h av = *(const v8h*)&Vb[(ht * 16 + l15) * 72 + ks * 32 + quad * 8];
        O[ht][0] = __builtin_amdgcn_mfma_f32_16x16x32_f16(av, p0, O[ht][0], 0, 0, 0);
        O[ht][1] = __builtin_amdgcn_mfma_f32_16x16x32_f16(av, p1, O[ht][1], 0, 0, 0);
      }
      lacc[0] = __builtin_amdgcn_mfma_f32_16x16x32_f16(vones, p0, lacc[0], 0, 0, 0);
      lacc[1] = __builtin_amdgcn_mfma_f32_16x16x32_f16(vones, p1, lacc[1], 0, 0, 0);
    }
  }
  const int b = bh >> 4, hh = bh & 15;
  for (int nt = 0; nt < 2; ++nt) {
    float inv = 1.f / lacc[nt][0];                 // col sum of P, same in all 4 regs
    int q = qt0 + w * 32 + nt * 16 + l15;
    for (int ht = 0; ht < 4; ++ht) {
      v4h o4 = { (_Float16)(O[ht][nt][0] * inv), (_Float16)(O[ht][nt][1] * inv),
                 (_Float16)(O[ht][nt][2] * inv), (_Float16)(O[ht][nt][3] * inv) };
      *(v4h*)(ctx + ((size_t)q * 2 + b) * 1024 + hh * 64 + ht * 16 + quad * 4) = o4;
    }
  }
}

extern "C" void kernel_launch(void* const* d_in, const int* in_sizes, int n_in,
                              void* d_out, int out_size, void* d_ws, size_t ws_size,
                              hipStream_t stream) {
  (void)in_sizes; (void)n_in; (void)out_size; (void)ws_size;
  const float* query = (const float*)d_in[0];
  const float* key_  = (const float*)d_in[1];
  const float* value = (const float*)d_in[2];
  const float* wq = (const float*)d_in[3];
  const float* bq = (const float*)d_in[4];
  const float* wk = (const float*)d_in[5];
  const float* bk = (const float*)d_in[6];
  const float* wv = (const float*)d_in[7];
  const float* bv = (const float*)d_in[8];
  const float* wo = (const float*)d_in[9];
  const float* bo = (const float*)d_in[10];
  const float* wte = (const float*)d_in[11];
  const float* w1 = (const float*)d_in[12];
  const float* b1 = (const float*)d_in[13];
  const float* w2 = (const float*)d_in[14];
  const float* b2 = (const float*)d_in[15];
  const int* lang = (const int*)d_in[16];
  float* out = (float*)d_out;

  const size_t NTB = (size_t)T_SEQ * BATCH * DIM;   // 4194304
  const size_t DD  = (size_t)DIM * DIM;             // 1048576
  const size_t KVN = (size_t)BATCH * NH * TKP * HD; // 4325376
  _Float16* xq  = (_Float16*)d_ws;
  _Float16* xk  = xq + NTB;
  _Float16* xv  = xk + NTB;
  _Float16* wqb = xv + NTB;
  _Float16* wkb = wqb + DD;
  _Float16* wvb = wkb + DD;
  _Float16* wob = wvb + DD;
  _Float16* qbuf = wob + DD;
  _Float16* kbuf = qbuf + NTB;
  _Float16* vbuf = kbuf + KVN;
  float* hbuf = (float*)(vbuf + KVN);
  _Float16* ctxb = xq;   // alias: xq is dead after the QKV projections

  cvt_all<<<16384, 256, 0, stream>>>((const float4*)query, (const float4*)key_,
                                     (const float4*)value, (const float4*)wq,
                                     (const float4*)wk, (const float4*)wv, (const float4*)wo,
                                     (v4h*)xq, (v4h*)xk, (v4h*)xv, (v4h*)wqb,
                                     (v4h*)wkb, (v4h*)wvb, (v4h*)wob);
  pad_k<<<32, 256, 0, stream>>>(kbuf, vbuf);
  prefix_h_k<<<400, 256, 0, stream>>>(wte, w1, b1, lang, hbuf);
  prefix_kv_k<<<1024, 256, 0, stream>>>(w2, b2, hbuf, lang, kbuf, vbuf);
  gemm_bt_k<<<dim3(32, 8, 3), 256, 0, stream>>>(xq, xk, xv, wqb, wkb, wvb, bq, bk, bv,
                                                qbuf, kbuf, vbuf, nullptr, 0);
  attn_k<<<dim3(32, 16), 256, 0, stream>>>(qbuf, kbuf, vbuf, ctxb);
  gemm_bt_k<<<dim3(32, 8, 1), 256, 0, stream>>>(ctxb, ctxb, ctxb, wob, wob, wob, bo, bo, bo,
                                                qbuf, kbuf, vbuf, out, 3);
}

// Round 5
// 297.952 us; speedup vs baseline: 1.0742x; 1.0321x over previous
//
#include <hip/hip_runtime.h>
#include <stdint.h>

// Problem constants
#define T_SEQ 2048
#define BATCH 2
#define DIM   1024
#define NH    16
#define HD    64
#define TKP   2112   // padded key rows: keys 0..2047, prefix at 2048, zeros 2049..2111

typedef _Float16 v8h __attribute__((ext_vector_type(8)));
typedef _Float16 v4h __attribute__((ext_vector_type(4)));
typedef float    f32x4 __attribute__((ext_vector_type(4)));
typedef float    f32x16 __attribute__((ext_vector_type(16)));

// async global->LDS, 16B per lane; LDS dst must be wave-uniform base (lane*16 auto)
__device__ __forceinline__ void gload16(const _Float16* g, _Float16* l) {
  __builtin_amdgcn_global_load_lds(
      (__attribute__((address_space(1))) unsigned int*)g,
      (__attribute__((address_space(3))) unsigned int*)l, 16, 0, 0);
}

// ---------------- fused f32 -> f16 convert (q,k,v,wq,wk,wv,wo in one launch) ------
__global__ void cvt_all(const float4* __restrict__ s0, const float4* __restrict__ s1,
                        const float4* __restrict__ s2, const float4* __restrict__ s3,
                        const float4* __restrict__ s4, const float4* __restrict__ s5,
                        const float4* __restrict__ s6,
                        v4h* __restrict__ d0, v4h* __restrict__ d1, v4h* __restrict__ d2,
                        v4h* __restrict__ d3, v4h* __restrict__ d4, v4h* __restrict__ d5,
                        v4h* __restrict__ d6) {
  const int NTB4 = 1048576, DD4 = 262144;      // float4 counts
  int i = blockIdx.x * 256 + threadIdx.x;      // 0..4194303
  const float4* s; v4h* d; int off;
  if (i < 3 * NTB4) {
    int t = i / NTB4; off = i - t * NTB4;
    s = t == 0 ? s0 : t == 1 ? s1 : s2;
    d = t == 0 ? d0 : t == 1 ? d1 : d2;
  } else {
    int j = i - 3 * NTB4;
    int t = j / DD4; off = j - t * DD4;
    s = t == 0 ? s3 : t == 1 ? s4 : t == 2 ? s5 : s6;
    d = t == 0 ? d3 : t == 1 ? d4 : t == 2 ? d5 : d6;
  }
  float4 v = s[off];
  v4h o = { (_Float16)v.x, (_Float16)v.y, (_Float16)v.z, (_Float16)v.w };
  d[off] = o;
}

// ---------------- prefix MLP stage 1 + K/V pad zeroing (merged: one launch) ------
__global__ void prefix_pad_k(const float* __restrict__ wte, const float* __restrict__ w1,
                             const float* __restrict__ b1, const int* __restrict__ lang,
                             float* __restrict__ hbuf,
                             _Float16* __restrict__ kb, _Float16* __restrict__ vb) {
  if (blockIdx.x >= 400) {
    // pad part: zero key rows 2048..2111 / V cols 2048..2111 (prefix_kv_k then
    // overwrites slot 2048). Contiguous 16B stores.
    int bh = blockIdx.x - 400;
    v8h z = {};
    _Float16* kp = kb + ((size_t)bh * TKP + 2048) * 64;    // 64 rows x 64 = contiguous
    for (int i = threadIdx.x; i < 512; i += 256) *(v8h*)&kp[i * 8] = z;
    for (int i = threadIdx.x; i < 512; i += 256) {         // 64 hd-rows x 64 t, 8 segs
      int c = i >> 3, seg = i & 7;
      *(v8h*)&vb[((size_t)bh * 64 + c) * TKP + 2048 + seg * 8] = z;
    }
    return;
  }
  int wid = blockIdx.x * 4 + (threadIdx.x >> 6);   // 0..1599 = b*800+j
  int lane = threadIdx.x & 63;
  int b = wid / 800, j = wid - b * 800;
  int c = lang[b];
  const float* wr = w1 + ((size_t)c * 800 + j) * 1024;
  const float* em = wte + (size_t)c * 1024;
  float s = 0.f;
  for (int d = lane; d < 1024; d += 64) s += wr[d] * em[d];
  for (int off = 32; off > 0; off >>= 1) s += __shfl_down(s, off, 64);
  if (lane == 0) hbuf[wid] = tanhf(s + b1[c * 800 + j]);
}

// kv[b,e]: e<1024 -> prefix K (key slot 2048), else prefix V (col slot 2048)
__global__ void prefix_kv_k(const float* __restrict__ w2, const float* __restrict__ b2,
                            const float* __restrict__ hbuf, const int* __restrict__ lang,
                            _Float16* __restrict__ kb, _Float16* __restrict__ vb) {
  int wid = blockIdx.x * 4 + (threadIdx.x >> 6);   // 0..4095 = b*2048+e
  int lane = threadIdx.x & 63;
  int b = wid >> 11, e = wid & 2047;
  int c = lang[b];
  const float* wr = w2 + ((size_t)c * 2048 + e) * 800;
  const float* hb = hbuf + b * 800;
  float s = 0.f;
  for (int j = lane; j < 800; j += 64) s += wr[j] * hb[j];
  for (int off = 32; off > 0; off >>= 1) s += __shfl_down(s, off, 64);
  if (lane == 0) {
    float val = s + b2[c * 2048 + e];
    if (e < 1024) {
      int h = e >> 6, hd = e & 63;
      kb[((size_t)(b * 16 + h) * TKP + 2048) * 64 + hd] = (_Float16)val;
    } else {
      int d = e - 1024;
      int h = d >> 6, hd = d & 63;
      vb[((size_t)(b * 16 + h) * 64 + hd) * TKP + 2048] = (_Float16)val;
    }
  }
}

// ---------------- gemm_bt: Out[r,e] = sum_d A[r,d]*W[e,d] + bias[e] ----------------
// 128x128 tile, BK=64, 4 waves 2x2, 16x16x32 f16 MFMA.
// blockIdx.x = row-tile (XCD swizzle: same rows land on same XCD), y = col-tile.
// mode 0: q (*0.125*log2e -> [B,H,T,hd]); 1: k (-> [B,H,t,hd], prefix at 2048);
// mode 2: v transposed (-> [B,H,hd,t]); 3: fp32 out (d_out [T,B,D], direct full-line stores)
// Epilogue (modes 0-2) restages through wave-private LDS (16B-aligned strides) so
// every global store instruction writes full 64B cache lines.
__global__ __launch_bounds__(256) void gemm_bt_k(
    const _Float16* __restrict__ A0, const _Float16* __restrict__ A1, const _Float16* __restrict__ A2,
    const _Float16* __restrict__ W0, const _Float16* __restrict__ W1, const _Float16* __restrict__ W2,
    const float* __restrict__ bs0, const float* __restrict__ bs1, const float* __restrict__ bs2,
    _Float16* __restrict__ qb, _Float16* __restrict__ kb, _Float16* __restrict__ vb,
    float* __restrict__ fout, int mode_base)
{
  __shared__ __align__(16) _Float16 smem[128 * 64 * 2];    // As | Bs, reused as epilogue stage
  _Float16* As = smem;
  _Float16* Bs = smem + 128 * 64;
  const int mode = mode_base + blockIdx.z;
  const _Float16* A = (mode == 1) ? A1 : (mode == 2) ? A2 : A0;
  const _Float16* W = (mode == 1) ? W1 : (mode == 2) ? W2 : W0;
  const float* bias = (mode == 1) ? bs1 : (mode == 2) ? bs2 : bs0;
  const int tid = threadIdx.x, w = tid >> 6, lane = tid & 63;
  const int quad = lane >> 4, l15 = lane & 15;
  const int r0 = blockIdx.x * 128, c0 = blockIdx.y * 128;
  const int wm = w >> 1, wn = w & 1;
  const int srow = lane >> 3, sseg = lane & 7;
  f32x4 acc[4][4] = {};
  for (int k0 = 0; k0 < 1024; k0 += 64) {
    for (int i = 0; i < 4; ++i) {
      int rowb = w * 32 + i * 8;
      gload16(A + (size_t)(r0 + rowb + srow) * 1024 + k0 + sseg * 8, &As[rowb * 64]);
      gload16(W + (size_t)(c0 + rowb + srow) * 1024 + k0 + sseg * 8, &Bs[rowb * 64]);
    }
    __syncthreads();
    for (int ks = 0; ks < 2; ++ks) {
      v8h af[4], bfr[4];
      for (int mt = 0; mt < 4; ++mt)
        af[mt] = *(const v8h*)&As[(wm * 64 + mt * 16 + l15) * 64 + ks * 32 + quad * 8];
      for (int nt = 0; nt < 4; ++nt)
        bfr[nt] = *(const v8h*)&Bs[(wn * 64 + nt * 16 + l15) * 64 + ks * 32 + quad * 8];
      for (int mt = 0; mt < 4; ++mt)
        for (int nt = 0; nt < 4; ++nt)
          acc[mt][nt] = __builtin_amdgcn_mfma_f32_16x16x32_f16(af[mt], bfr[nt], acc[mt][nt], 0, 0, 0);
    }
    __syncthreads();
  }
  // ---- epilogue; C/D layout: col = lane&15, row = quad*4 + reg ----
  if (mode == 3) {
    // fp32 direct: 16 l15-lanes x 4B = one full 64B line per quad. Already ideal.
    for (int nt = 0; nt < 4; ++nt) {
      int e = c0 + wn * 64 + nt * 16 + l15;
      float be = bias[e];
      for (int mt = 0; mt < 4; ++mt) {
        int rb = r0 + wm * 64 + mt * 16 + quad * 4;
        for (int reg = 0; reg < 4; ++reg)
          fout[(size_t)(rb + reg) * 1024 + e] = acc[mt][nt][reg] + be;
      }
    }
    return;
  }
  _Float16* st = smem + w * 4096;                  // wave-private stage (8192 B)
  // mode 0: fold softmax's log2(e) into the Q scale so attn can use raw v_exp_f32
  const float qscale = (mode == 0) ? 0.125f * 1.44269504088896341f : 1.0f;
  for (int p = 0; p < 2; ++p) {                    // pass = half of the e-range (32 cols)
    __syncthreads();
    for (int ntl = 0; ntl < 2; ++ntl) {
      int nt = p * 2 + ntl;
      int e = c0 + wn * 64 + nt * 16 + l15;
      float be = bias[e];
      for (int mt = 0; mt < 4; ++mt)
        for (int reg = 0; reg < 4; ++reg) {
          float val = (acc[mt][nt][reg] + be) * qscale;
          int rl = mt * 16 + quad * 4 + reg;       // 0..63 local row
          if (mode != 2) st[rl * 40 + ntl * 16 + l15] = (_Float16)val;       // stride 40: 80B, 16B-mult
          else st[(ntl * 16 + l15) * 72 + (rl & 1) * 32 + (rl >> 1)] = (_Float16)val;  // stride 72: 144B
        }
    }
    __syncthreads();
    if (mode != 2) {
      // st[row r (64)][e (32), stride 40]; 4-lane groups write full 64B lines
      for (int it = 0; it < 4; ++it) {
        int chunk = it * 64 + lane;                // 0..255
        int rr = chunk >> 2, seg = chunk & 3;
        v8h val = *(const v8h*)&st[rr * 40 + seg * 8];
        int r = r0 + wm * 64 + rr, b = r & 1, t = r >> 1;
        int e0 = c0 + wn * 64 + p * 32 + seg * 8;
        int h = e0 >> 6, hd0 = e0 & 63;
        if (mode == 0) *(v8h*)&qb[((size_t)(b * 16 + h) * 2048 + t) * 64 + hd0] = val;
        else           *(v8h*)&kb[((size_t)(b * 16 + h) * TKP + t) * 64 + hd0] = val;
      }
    } else {
      // st[e (32), stride 72][b(2)*32 + t(32)]; 4-lane groups write full 64B lines
      for (int it = 0; it < 4; ++it) {
        int chunk = it * 64 + lane;                // 0..255
        int el = chunk >> 3, b = (chunk >> 2) & 1, qs = chunk & 3;
        v8h val = *(const v8h*)&st[el * 72 + b * 32 + qs * 8];
        int e = c0 + wn * 64 + p * 32 + el;
        int h = e >> 6, hd = e & 63;
        int t0 = ((r0 + wm * 64) >> 1) + qs * 8;
        *(v8h*)&vb[((size_t)(b * 16 + h) * 64 + hd) * TKP + t0] = val;
      }
    }
  }
}

// ---------------- flash attention (v6: 32x32 MFMA, NO cross-lane exchange) --------
// v5/v5b post-mortem: both permlane32_swap directions failed (9.3e-3 / 2.9e-2) --
// the exchange primitive's semantics can't be pinned down in this harness. But the
// small error magnitude proves QK^T, C/D layout, masking and epilogue are correct.
// v6 removes the exchange entirely: MFMA pairs A-slot(hi,j) with B-slot(hi,j)
// (kappa_A == kappa_B, evidenced by QK^T correctness), so we DEFINE the PV
// key-at-slot to be what each lane already holds from the S C-layout:
//   key(c,hi,j) = c*16 + (j&3) + 8*(j>>2) + 4*hi
// P fragment = pack of the lane's own 8 exp'd S registers (no shuffle at all).
// V is staged with the matching sigma permutation (within each 16-key chunk,
// swap key bits 2<->3: k0-3->pos0-3, k4-7->pos8-11, k8-11->pos4-7, k12-15->12-15)
// via two 8B writes per 16B chunk; the PV read addressing is unchanged from v5.
// LDS 36.9KB (Ks/Vs dbuf only); softmax denom in regs + one shfl_xor(32) at end.
__global__ __launch_bounds__(256) void attn_k(
    const _Float16* __restrict__ qb, const _Float16* __restrict__ kb,
    const _Float16* __restrict__ vb, _Float16* __restrict__ ctx)
{
  __shared__ __align__(16) _Float16 Ks[2][64 * 72];
  __shared__ __align__(16) _Float16 Vs[2][64 * 72];
  const int bh = blockIdx.x;
  const int qt0 = blockIdx.y * 128;
  const int tid = threadIdx.x, w = tid >> 6, lane = tid & 63;
  const int l31 = lane & 31, h8 = (lane >> 5) * 8;
  // loop-invariant Q fragments (B-operand, 32x32x16): n = l31 (query), k = t*16+h8+j
  v8h qf[4];
#pragma unroll
  for (int t = 0; t < 4; ++t)
    qf[t] = *(const v8h*)(qb + ((size_t)bh * 2048 + qt0 + w * 32 + l31) * 64 + t * 16 + h8);
  // staging coords: row = tid>>3 (0..31, +32 for second half), seg = tid&7
  const int sr = tid >> 3, sseg = tid & 7;
  const _Float16* kptr = kb + (size_t)bh * TKP * 64 + sr * 64 + sseg * 8;
  const _Float16* vptr = vb + (size_t)bh * 64 * TKP + (size_t)sr * TKP + sseg * 8;
  int4 kp0 = *(const int4*)kptr, kp1 = *(const int4*)(kptr + 2048);
  int4 vp0 = *(const int4*)vptr, vp1 = *(const int4*)(vptr + 32 * TKP);
  kptr += 4096; vptr += 64;
  // sigma staging byte-col of this thread's first 4-key group within its V row:
  // keys sseg*8..+3 -> chunk c=sseg>>1, half (sseg&1): col = c*32 + (sseg&1)*8;
  // keys sseg*8+4..+7 -> col + 16.
  const int vcb = (sseg >> 1) * 32 + (sseg & 1) * 8;
  f32x16 O0 = {}, O1 = {};
  float l_ = 0.f;
  for (int kc = 0; kc < 33; ++kc) {
    _Float16* Kb = Ks[kc & 1];
    _Float16* Vb = Vs[kc & 1];
    // write chunk kc (in regs) to this iter's buffer; parity keeps it race-free
    // vs. waves still computing kc-1 on the other buffer.
    *(int4*)&Kb[sr * 72 + sseg * 8] = kp0;
    *(int4*)&Kb[(sr + 32) * 72 + sseg * 8] = kp1;
    {
      char* vr0 = (char*)&Vb[sr * 72];
      char* vr1 = (char*)&Vb[(sr + 32) * 72];
      *(int2*)(vr0 + vcb)      = *(int2*)&vp0;
      *(int2*)(vr0 + vcb + 16) = *((int2*)&vp0 + 1);
      *(int2*)(vr1 + vcb)      = *(int2*)&vp1;
      *(int2*)(vr1 + vcb + 16) = *((int2*)&vp1 + 1);
    }
    __syncthreads();
    if (kc < 32) {                                 // prefetch next chunk; lands during compute
      kp0 = *(const int4*)kptr; kp1 = *(const int4*)(kptr + 2048);
      vp0 = *(const int4*)vptr; vp1 = *(const int4*)(vptr + 32 * TKP);
      kptr += 4096; vptr += 64;
    }
    // S^T = K(64keys x 64d) . Q^T: two 32x32 key tiles, 4 k-steps of 16
    f32x16 S0 = {}, S1 = {};
    __builtin_amdgcn_s_setprio(1);
#pragma unroll
    for (int t = 0; t < 4; ++t) {
      v8h kf0 = *(const v8h*)&Kb[(l31) * 72 + t * 16 + h8];
      v8h kf1 = *(const v8h*)&Kb[(32 + l31) * 72 + t * 16 + h8];
      S0 = __builtin_amdgcn_mfma_f32_32x32x16_f16(kf0, qf[t], S0, 0, 0, 0);
      S1 = __builtin_amdgcn_mfma_f32_32x32x16_f16(kf1, qf[t], S1, 0, 0, 0);
    }
    __builtin_amdgcn_s_setprio(0);
    if (kc == 32) {             // local key 0 = prefix (valid, tile0/hi=0/reg0); rest pad
#pragma unroll
      for (int r = 0; r < 16; ++r) {
        if (r > 0) S0[r] = -1e30f;
        S1[r] = -1e30f;
      }
      if (lane >= 32) S0[0] = -1e30f;
    }
    // softmax-lite: P = exp2(S) (log2e folded into Q projection); sum in regs
    float rs = 0.f;
#pragma unroll
    for (int r = 0; r < 16; ++r) { S0[r] = __builtin_amdgcn_exp2f(S0[r]); rs += S0[r]; }
#pragma unroll
    for (int r = 0; r < 16; ++r) { S1[r] = __builtin_amdgcn_exp2f(S1[r]); rs += S1[r]; }
    l_ += rs;
    // O^T += V^T(64hd x 64keys) . P: B-fragment = lane's OWN exp'd S regs
    // (key-at-slot matches sigma-staged V; no cross-lane ops).
    __builtin_amdgcn_s_setprio(1);
#pragma unroll
    for (int c = 0; c < 4; ++c) {
      v8h ph;
      if (c == 0)      ph = (v8h){ (_Float16)S0[0], (_Float16)S0[1], (_Float16)S0[2], (_Float16)S0[3],
                                   (_Float16)S0[4], (_Float16)S0[5], (_Float16)S0[6], (_Float16)S0[7] };
      else if (c == 1) ph = (v8h){ (_Float16)S0[8], (_Float16)S0[9], (_Float16)S0[10], (_Float16)S0[11],
                                   (_Float16)S0[12], (_Float16)S0[13], (_Float16)S0[14], (_Float16)S0[15] };
      else if (c == 2) ph = (v8h){ (_Float16)S1[0], (_Float16)S1[1], (_Float16)S1[2], (_Float16)S1[3],
                                   (_Float16)S1[4], (_Float16)S1[5], (_Float16)S1[6], (_Float16)S1[7] };
      else             ph = (v8h){ (_Float16)S1[8], (_Float16)S1[9], (_Float16)S1[10], (_Float16)S1[11],
                                   (_Float16)S1[12], (_Float16)S1[13], (_Float16)S1[14], (_Float16)S1[15] };
      v8h vf0 = *(const v8h*)&Vb[(l31) * 72 + c * 16 + h8];
      v8h vf1 = *(const v8h*)&Vb[(32 + l31) * 72 + c * 16 + h8];
      O0 = __builtin_amdgcn_mfma_f32_32x32x16_f16(vf0, ph, O0, 0, 0, 0);
      O1 = __builtin_amdgcn_mfma_f32_32x32x16_f16(vf1, ph, O1, 0, 0, 0);
    }
    __builtin_amdgcn_s_setprio(0);
  }
  // lanes l and l+32 hold the same query column (halves of the key rows)
  l_ += __shfl_xor(l_, 32, 64);
  const float inv = 1.f / l_;
  const int b = bh >> 4, hh = bh & 15;
  const int q = qt0 + w * 32 + l31;
  _Float16* cbase = ctx + ((size_t)q * 2 + b) * 1024 + hh * 64 + (h8 >> 1);  // +4*hi
#pragma unroll
  for (int rq = 0; rq < 4; ++rq) {
    v4h o0 = { (_Float16)(O0[rq * 4 + 0] * inv), (_Float16)(O0[rq * 4 + 1] * inv),
               (_Float16)(O0[rq * 4 + 2] * inv), (_Float16)(O0[rq * 4 + 3] * inv) };
    *(v4h*)(cbase + rq * 8) = o0;
    v4h o1 = { (_Float16)(O1[rq * 4 + 0] * inv), (_Float16)(O1[rq * 4 + 1] * inv),
               (_Float16)(O1[rq * 4 + 2] * inv), (_Float16)(O1[rq * 4 + 3] * inv) };
    *(v4h*)(cbase + 32 + rq * 8) = o1;
  }
}

extern "C" void kernel_launch(void* const* d_in, const int* in_sizes, int n_in,
                              void* d_out, int out_size, void* d_ws, size_t ws_size,
                              hipStream_t stream) {
  (void)in_sizes; (void)n_in; (void)out_size; (void)ws_size;
  const float* query = (const float*)d_in[0];
  const float* key_  = (const float*)d_in[1];
  const float* value = (const float*)d_in[2];
  const float* wq = (const float*)d_in[3];
  const float* bq = (const float*)d_in[4];
  const float* wk = (const float*)d_in[5];
  const float* bk = (const float*)d_in[6];
  const float* wv = (const float*)d_in[7];
  const float* bv = (const float*)d_in[8];
  const float* wo = (const float*)d_in[9];
  const float* bo = (const float*)d_in[10];
  const float* wte = (const float*)d_in[11];
  const float* w1 = (const float*)d_in[12];
  const float* b1 = (const float*)d_in[13];
  const float* w2 = (const float*)d_in[14];
  const float* b2 = (const float*)d_in[15];
  const int* lang = (const int*)d_in[16];
  float* out = (float*)d_out;

  const size_t NTB = (size_t)T_SEQ * BATCH * DIM;   // 4194304
  const size_t DD  = (size_t)DIM * DIM;             // 1048576
  const size_t KVN = (size_t)BATCH * NH * TKP * HD; // 4325376
  _Float16* xq  = (_Float16*)d_ws;
  _Float16* xk  = xq + NTB;
  _Float16* xv  = xk + NTB;
  _Float16* wqb = xv + NTB;
  _Float16* wkb = wqb + DD;
  _Float16* wvb = wkb + DD;
  _Float16* wob = wvb + DD;
  _Float16* qbuf = wob + DD;
  _Float16* kbuf = qbuf + NTB;
  _Float16* vbuf = kbuf + KVN;
  float* hbuf = (float*)(vbuf + KVN);
  _Float16* ctxb = xq;   // alias: xq is dead after the QKV projections

  cvt_all<<<16384, 256, 0, stream>>>((const float4*)query, (const float4*)key_,
                                     (const float4*)value, (const float4*)wq,
                                     (const float4*)wk, (const float4*)wv, (const float4*)wo,
                                     (v4h*)xq, (v4h*)xk, (v4h*)xv, (v4h*)wqb,
                                     (v4h*)wkb, (v4h*)wvb, (v4h*)wob);
  prefix_pad_k<<<432, 256, 0, stream>>>(wte, w1, b1, lang, hbuf, kbuf, vbuf);
  prefix_kv_k<<<1024, 256, 0, stream>>>(w2, b2, hbuf, lang, kbuf, vbuf);
  gemm_bt_k<<<dim3(32, 8, 3), 256, 0, stream>>>(xq, xk, xv, wqb, wkb, wvb, bq, bk, bv,
                                                qbuf, kbuf, vbuf, nullptr, 0);
  attn_k<<<dim3(32, 16), 256, 0, stream>>>(qbuf, kbuf, vbuf, ctxb);
  gemm_bt_k<<<dim3(32, 8, 1), 256, 0, stream>>>(ctxb, ctxb, ctxb, wob, wob, wob, bo, bo, bo,
                                                qbuf, kbuf, vbuf, out, 3);
}

// Round 6
// 276.443 us; speedup vs baseline: 1.1578x; 1.0778x over previous
//
#include <hip/hip_runtime.h>
#include <stdint.h>

// Problem constants
#define T_SEQ 2048
#define BATCH 2
#define DIM   1024
#define NH    16
#define HD    64
#define TKP   2112   // padded key rows: keys 0..2047, prefix at 2048, zeros 2049..2111

typedef _Float16 v8h __attribute__((ext_vector_type(8)));
typedef _Float16 v4h __attribute__((ext_vector_type(4)));
typedef float    f32x4 __attribute__((ext_vector_type(4)));
typedef float    f32x16 __attribute__((ext_vector_type(16)));

// async global->LDS, 16B per lane; LDS dst must be wave-uniform base (lane*16 auto)
__device__ __forceinline__ void gload16(const _Float16* g, _Float16* l) {
  __builtin_amdgcn_global_load_lds(
      (__attribute__((address_space(1))) unsigned int*)g,
      (__attribute__((address_space(3))) unsigned int*)l, 16, 0, 0);
}

// ---------------- fused f32 -> f16 convert (q,k,v,wq,wk,wv,wo in one launch) ------
__global__ void cvt_all(const float4* __restrict__ s0, const float4* __restrict__ s1,
                        const float4* __restrict__ s2, const float4* __restrict__ s3,
                        const float4* __restrict__ s4, const float4* __restrict__ s5,
                        const float4* __restrict__ s6,
                        v4h* __restrict__ d0, v4h* __restrict__ d1, v4h* __restrict__ d2,
                        v4h* __restrict__ d3, v4h* __restrict__ d4, v4h* __restrict__ d5,
                        v4h* __restrict__ d6) {
  const int NTB4 = 1048576, DD4 = 262144;      // float4 counts
  int i = blockIdx.x * 256 + threadIdx.x;      // 0..4194303
  const float4* s; v4h* d; int off;
  if (i < 3 * NTB4) {
    int t = i / NTB4; off = i - t * NTB4;
    s = t == 0 ? s0 : t == 1 ? s1 : s2;
    d = t == 0 ? d0 : t == 1 ? d1 : d2;
  } else {
    int j = i - 3 * NTB4;
    int t = j / DD4; off = j - t * DD4;
    s = t == 0 ? s3 : t == 1 ? s4 : t == 2 ? s5 : s6;
    d = t == 0 ? d3 : t == 1 ? d4 : t == 2 ? d5 : d6;
  }
  float4 v = s[off];
  v4h o = { (_Float16)v.x, (_Float16)v.y, (_Float16)v.z, (_Float16)v.w };
  d[off] = o;
}

// ---------------- prefix MLP stage 1 + K/V pad zeroing (merged: one launch) ------
__global__ void prefix_pad_k(const float* __restrict__ wte, const float* __restrict__ w1,
                             const float* __restrict__ b1, const int* __restrict__ lang,
                             float* __restrict__ hbuf,
                             _Float16* __restrict__ kb, _Float16* __restrict__ vb) {
  if (blockIdx.x >= 400) {
    // pad part: zero key rows 2048..2111 / V cols 2048..2111 (prefix_kv_k then
    // overwrites slot 2048). Contiguous 16B stores.
    int bh = blockIdx.x - 400;
    v8h z = {};
    _Float16* kp = kb + ((size_t)bh * TKP + 2048) * 64;    // 64 rows x 64 = contiguous
    for (int i = threadIdx.x; i < 512; i += 256) *(v8h*)&kp[i * 8] = z;
    for (int i = threadIdx.x; i < 512; i += 256) {         // 64 hd-rows x 64 t, 8 segs
      int c = i >> 3, seg = i & 7;
      *(v8h*)&vb[((size_t)bh * 64 + c) * TKP + 2048 + seg * 8] = z;
    }
    return;
  }
  int wid = blockIdx.x * 4 + (threadIdx.x >> 6);   // 0..1599 = b*800+j
  int lane = threadIdx.x & 63;
  int b = wid / 800, j = wid - b * 800;
  int c = lang[b];
  const float* wr = w1 + ((size_t)c * 800 + j) * 1024;
  const float* em = wte + (size_t)c * 1024;
  float s = 0.f;
  for (int d = lane; d < 1024; d += 64) s += wr[d] * em[d];
  for (int off = 32; off > 0; off >>= 1) s += __shfl_down(s, off, 64);
  if (lane == 0) hbuf[wid] = tanhf(s + b1[c * 800 + j]);
}

// kv[b,e]: e<1024 -> prefix K (key slot 2048), else prefix V (col slot 2048)
__global__ void prefix_kv_k(const float* __restrict__ w2, const float* __restrict__ b2,
                            const float* __restrict__ hbuf, const int* __restrict__ lang,
                            _Float16* __restrict__ kb, _Float16* __restrict__ vb) {
  int wid = blockIdx.x * 4 + (threadIdx.x >> 6);   // 0..4095 = b*2048+e
  int lane = threadIdx.x & 63;
  int b = wid >> 11, e = wid & 2047;
  int c = lang[b];
  const float* wr = w2 + ((size_t)c * 2048 + e) * 800;
  const float* hb = hbuf + b * 800;
  float s = 0.f;
  for (int j = lane; j < 800; j += 64) s += wr[j] * hb[j];
  for (int off = 32; off > 0; off >>= 1) s += __shfl_down(s, off, 64);
  if (lane == 0) {
    float val = s + b2[c * 2048 + e];
    if (e < 1024) {
      int h = e >> 6, hd = e & 63;
      kb[((size_t)(b * 16 + h) * TKP + 2048) * 64 + hd] = (_Float16)val;
    } else {
      int d = e - 1024;
      int h = d >> 6, hd = d & 63;
      vb[((size_t)(b * 16 + h) * 64 + hd) * TKP + 2048] = (_Float16)val;
    }
  }
}

// ---------------- gemm_bt: Out[r,e] = sum_d A[r,d]*W[e,d] + bias[e] ----------------
// 128x128 tile, BK=64, 4 waves 2x2, 16x16x32 f16 MFMA.
// v7 K-loop (was m97-style stage->sync->compute->sync, 59us @ MfmaUtil 16%,
// 9.7M bank-conflict cycles = 27% of time, all pipes <20% = phase-serialized):
//  - DOUBLE-BUFFERED LDS (64KB) + issue-ahead: stage(t+1) issued BEFORE compute(t),
//    raw s_barrier + counted "s_waitcnt vmcnt(8)" (never 0 in-loop) so the 8
//    loads of t+1 stay in flight under compute(t). Two barriers/step keep the
//    DMA-vs-read buffer reuse race-free; sched_barrier(0) fences hoisting.
//  - T2 XOR-swizzle on As/Bs (both-sides-or-neither): staging pre-swizzles the
//    GLOBAL source segment (sseg^srow, LDS dest stays linear for global_load_lds),
//    reads use slot^(l15&7). 128B-stride rows were a 16-way bank conflict; now
//    lanes spread over 8 bank groups (2-way = free).
// mode 0: q (*0.125*log2e -> [B,H,T,hd]); 1: k (-> [B,H,t,hd], prefix at 2048);
// mode 2: v transposed (-> [B,H,hd,t]); 3: fp32 out (d_out [T,B,D], direct stores)
__global__ __launch_bounds__(256) void gemm_bt_k(
    const _Float16* __restrict__ A0, const _Float16* __restrict__ A1, const _Float16* __restrict__ A2,
    const _Float16* __restrict__ W0, const _Float16* __restrict__ W1, const _Float16* __restrict__ W2,
    const float* __restrict__ bs0, const float* __restrict__ bs1, const float* __restrict__ bs2,
    _Float16* __restrict__ qb, _Float16* __restrict__ kb, _Float16* __restrict__ vb,
    float* __restrict__ fout, int mode_base)
{
  __shared__ __align__(16) _Float16 smem[2][128 * 64 * 2];   // [buf][As|Bs]
  const int mode = mode_base + blockIdx.z;
  const _Float16* A = (mode == 1) ? A1 : (mode == 2) ? A2 : A0;
  const _Float16* W = (mode == 1) ? W1 : (mode == 2) ? W2 : W0;
  const float* bias = (mode == 1) ? bs1 : (mode == 2) ? bs2 : bs0;
  const int tid = threadIdx.x, w = tid >> 6, lane = tid & 63;
  const int quad = lane >> 4, l15 = lane & 15;
  const int r0 = blockIdx.x * 128, c0 = blockIdx.y * 128;
  const int wm = w >> 1, wn = w & 1;
  const int srow = lane >> 3, sseg = lane & 7;   // srow 0..7, sseg 0..7
  const int sw_seg = sseg ^ srow;                // pre-swizzled global segment
  const int rsw = l15 & 7;                       // read-side row-XOR
  f32x4 acc[4][4] = {};

  // stage K-step tile k0 into buffer p (8 gload_lds per wave)
  auto stage = [&](int k0, int p) {
    _Float16* As = smem[p];
    _Float16* Bs = smem[p] + 8192;
#pragma unroll
    for (int i = 0; i < 4; ++i) {
      int rowb = w * 32 + i * 8;
      gload16(A + (size_t)(r0 + rowb + srow) * 1024 + k0 + sw_seg * 8, &As[rowb * 64]);
      gload16(W + (size_t)(c0 + rowb + srow) * 1024 + k0 + sw_seg * 8, &Bs[rowb * 64]);
    }
  };

  stage(0, 0);                                   // prologue: 8 outstanding
  for (int t = 0; t < 16; ++t) {
    if (t < 15) {
      stage((t + 1) << 6, (t + 1) & 1);          // 16 outstanding
      asm volatile("s_waitcnt vmcnt(8)" ::: "memory");   // wait ONLY step t's 8
    } else {
      asm volatile("s_waitcnt vmcnt(0)" ::: "memory");
    }
    __builtin_amdgcn_s_barrier();                // all waves' buf[t] complete
    __builtin_amdgcn_sched_barrier(0);
    const _Float16* As = smem[t & 1];
    const _Float16* Bs = smem[t & 1] + 8192;
#pragma unroll
    for (int ks = 0; ks < 2; ++ks) {
      v8h af[4], bfr[4];
#pragma unroll
      for (int mt = 0; mt < 4; ++mt)
        af[mt] = *(const v8h*)&As[(wm * 64 + mt * 16 + l15) * 64 + (((ks * 4 + quad) ^ rsw) * 8)];
#pragma unroll
      for (int nt = 0; nt < 4; ++nt)
        bfr[nt] = *(const v8h*)&Bs[(wn * 64 + nt * 16 + l15) * 64 + (((ks * 4 + quad) ^ rsw) * 8)];
#pragma unroll
      for (int mt = 0; mt < 4; ++mt)
#pragma unroll
        for (int nt = 0; nt < 4; ++nt)
          acc[mt][nt] = __builtin_amdgcn_mfma_f32_16x16x32_f16(af[mt], bfr[nt], acc[mt][nt], 0, 0, 0);
    }
    __builtin_amdgcn_sched_barrier(0);
    __builtin_amdgcn_s_barrier();                // reads of buf[t] done before its next DMA
  }
  // ---- epilogue; C/D layout: col = lane&15, row = quad*4 + reg ----
  if (mode == 3) {
    // fp32 direct: 16 l15-lanes x 4B = one full 64B line per quad. Already ideal.
    for (int nt = 0; nt < 4; ++nt) {
      int e = c0 + wn * 64 + nt * 16 + l15;
      float be = bias[e];
      for (int mt = 0; mt < 4; ++mt) {
        int rb = r0 + wm * 64 + mt * 16 + quad * 4;
        for (int reg = 0; reg < 4; ++reg)
          fout[(size_t)(rb + reg) * 1024 + e] = acc[mt][nt][reg] + be;
      }
    }
    return;
  }
  _Float16* st = &smem[0][0] + w * 4096;         // wave-private stage (8192 B)
  // mode 0: fold softmax's log2(e) into the Q scale so attn can use raw v_exp_f32
  const float qscale = (mode == 0) ? 0.125f * 1.44269504088896341f : 1.0f;
  for (int p = 0; p < 2; ++p) {                  // pass = half of the e-range (32 cols)
    __syncthreads();
    for (int ntl = 0; ntl < 2; ++ntl) {
      int nt = p * 2 + ntl;
      int e = c0 + wn * 64 + nt * 16 + l15;
      float be = bias[e];
      for (int mt = 0; mt < 4; ++mt)
        for (int reg = 0; reg < 4; ++reg) {
          float val = (acc[mt][nt][reg] + be) * qscale;
          int rl = mt * 16 + quad * 4 + reg;     // 0..63 local row
          if (mode != 2) st[rl * 40 + ntl * 16 + l15] = (_Float16)val;       // stride 40: 80B, 16B-mult
          else st[(ntl * 16 + l15) * 72 + (rl & 1) * 32 + (rl >> 1)] = (_Float16)val;  // stride 72: 144B
        }
    }
    __syncthreads();
    if (mode != 2) {
      // st[row r (64)][e (32), stride 40]; 4-lane groups write full 64B lines
      for (int it = 0; it < 4; ++it) {
        int chunk = it * 64 + lane;              // 0..255
        int rr = chunk >> 2, seg = chunk & 3;
        v8h val = *(const v8h*)&st[rr * 40 + seg * 8];
        int r = r0 + wm * 64 + rr, b = r & 1, t = r >> 1;
        int e0 = c0 + wn * 64 + p * 32 + seg * 8;
        int h = e0 >> 6, hd0 = e0 & 63;
        if (mode == 0) *(v8h*)&qb[((size_t)(b * 16 + h) * 2048 + t) * 64 + hd0] = val;
        else           *(v8h*)&kb[((size_t)(b * 16 + h) * TKP + t) * 64 + hd0] = val;
      }
    } else {
      // st[e (32), stride 72][b(2)*32 + t(32)]; 4-lane groups write full 64B lines
      for (int it = 0; it < 4; ++it) {
        int chunk = it * 64 + lane;              // 0..255
        int el = chunk >> 3, b = (chunk >> 2) & 1, qs = chunk & 3;
        v8h val = *(const v8h*)&st[el * 72 + b * 32 + qs * 8];
        int e = c0 + wn * 64 + p * 32 + el;
        int h = e >> 6, hd = e & 63;
        int t0 = ((r0 + wm * 64) >> 1) + qs * 8;
        *(v8h*)&vb[((size_t)(b * 16 + h) * 64 + hd) * TKP + t0] = val;
      }
    }
  }
}

// ---------------- flash attention (v6: 32x32 MFMA, NO cross-lane exchange) --------
// MFMA pairs A-slot(hi,j) with B-slot(hi,j), so the PV key-at-slot is DEFINED to
// be what each lane already holds from the S C-layout:
//   key(c,hi,j) = c*16 + (j&3) + 8*(j>>2) + 4*hi
// P fragment = pack of the lane's own 8 exp'd S registers (no shuffle at all).
// V is staged with the matching sigma permutation (within each 16-key chunk,
// swap key bits 2<->3) via two 8B writes per 16B chunk; PV read addressing
// is the natural one. LDS 36.9KB (Ks/Vs dbuf); softmax denom in regs +
// one shfl_xor(32) at the end.
__global__ __launch_bounds__(256) void attn_k(
    const _Float16* __restrict__ qb, const _Float16* __restrict__ kb,
    const _Float16* __restrict__ vb, _Float16* __restrict__ ctx)
{
  __shared__ __align__(16) _Float16 Ks[2][64 * 72];
  __shared__ __align__(16) _Float16 Vs[2][64 * 72];
  const int bh = blockIdx.x;
  const int qt0 = blockIdx.y * 128;
  const int tid = threadIdx.x, w = tid >> 6, lane = tid & 63;
  const int l31 = lane & 31, h8 = (lane >> 5) * 8;
  // loop-invariant Q fragments (B-operand, 32x32x16): n = l31 (query), k = t*16+h8+j
  v8h qf[4];
#pragma unroll
  for (int t = 0; t < 4; ++t)
    qf[t] = *(const v8h*)(qb + ((size_t)bh * 2048 + qt0 + w * 32 + l31) * 64 + t * 16 + h8);
  // staging coords: row = tid>>3 (0..31, +32 for second half), seg = tid&7
  const int sr = tid >> 3, sseg = tid & 7;
  const _Float16* kptr = kb + (size_t)bh * TKP * 64 + sr * 64 + sseg * 8;
  const _Float16* vptr = vb + (size_t)bh * 64 * TKP + (size_t)sr * TKP + sseg * 8;
  int4 kp0 = *(const int4*)kptr, kp1 = *(const int4*)(kptr + 2048);
  int4 vp0 = *(const int4*)vptr, vp1 = *(const int4*)(vptr + 32 * TKP);
  kptr += 4096; vptr += 64;
  // sigma staging byte-col of this thread's first 4-key group within its V row:
  // keys sseg*8..+3 -> chunk c=sseg>>1, half (sseg&1): col = c*32 + (sseg&1)*8;
  // keys sseg*8+4..+7 -> col + 16.
  const int vcb = (sseg >> 1) * 32 + (sseg & 1) * 8;
  f32x16 O0 = {}, O1 = {};
  float l_ = 0.f;
  for (int kc = 0; kc < 33; ++kc) {
    _Float16* Kb = Ks[kc & 1];
    _Float16* Vb = Vs[kc & 1];
    // write chunk kc (in regs) to this iter's buffer; parity keeps it race-free
    // vs. waves still computing kc-1 on the other buffer.
    *(int4*)&Kb[sr * 72 + sseg * 8] = kp0;
    *(int4*)&Kb[(sr + 32) * 72 + sseg * 8] = kp1;
    {
      char* vr0 = (char*)&Vb[sr * 72];
      char* vr1 = (char*)&Vb[(sr + 32) * 72];
      *(int2*)(vr0 + vcb)      = *(int2*)&vp0;
      *(int2*)(vr0 + vcb + 16) = *((int2*)&vp0 + 1);
      *(int2*)(vr1 + vcb)      = *(int2*)&vp1;
      *(int2*)(vr1 + vcb + 16) = *((int2*)&vp1 + 1);
    }
    __syncthreads();
    if (kc < 32) {                                 // prefetch next chunk; lands during compute
      kp0 = *(const int4*)kptr; kp1 = *(const int4*)(kptr + 2048);
      vp0 = *(const int4*)vptr; vp1 = *(const int4*)(vptr + 32 * TKP);
      kptr += 4096; vptr += 64;
    }
    // S^T = K(64keys x 64d) . Q^T: two 32x32 key tiles, 4 k-steps of 16
    f32x16 S0 = {}, S1 = {};
    __builtin_amdgcn_s_setprio(1);
#pragma unroll
    for (int t = 0; t < 4; ++t) {
      v8h kf0 = *(const v8h*)&Kb[(l31) * 72 + t * 16 + h8];
      v8h kf1 = *(const v8h*)&Kb[(32 + l31) * 72 + t * 16 + h8];
      S0 = __builtin_amdgcn_mfma_f32_32x32x16_f16(kf0, qf[t], S0, 0, 0, 0);
      S1 = __builtin_amdgcn_mfma_f32_32x32x16_f16(kf1, qf[t], S1, 0, 0, 0);
    }
    __builtin_amdgcn_s_setprio(0);
    if (kc == 32) {             // local key 0 = prefix (valid, tile0/hi=0/reg0); rest pad
#pragma unroll
      for (int r = 0; r < 16; ++r) {
        if (r > 0) S0[r] = -1e30f;
        S1[r] = -1e30f;
      }
      if (lane >= 32) S0[0] = -1e30f;
    }
    // softmax-lite: P = exp2(S) (log2e folded into Q projection); sum in regs
    float rs = 0.f;
#pragma unroll
    for (int r = 0; r < 16; ++r) { S0[r] = __builtin_amdgcn_exp2f(S0[r]); rs += S0[r]; }
#pragma unroll
    for (int r = 0; r < 16; ++r) { S1[r] = __builtin_amdgcn_exp2f(S1[r]); rs += S1[r]; }
    l_ += rs;
    // O^T += V^T(64hd x 64keys) . P: B-fragment = lane's OWN exp'd S regs
    // (key-at-slot matches sigma-staged V; no cross-lane ops).
    __builtin_amdgcn_s_setprio(1);
#pragma unroll
    for (int c = 0; c < 4; ++c) {
      v8h ph;
      if (c == 0)      ph = (v8h){ (_Float16)S0[0], (_Float16)S0[1], (_Float16)S0[2], (_Float16)S0[3],
                                   (_Float16)S0[4], (_Float16)S0[5], (_Float16)S0[6], (_Float16)S0[7] };
      else if (c == 1) ph = (v8h){ (_Float16)S0[8], (_Float16)S0[9], (_Float16)S0[10], (_Float16)S0[11],
                                   (_Float16)S0[12], (_Float16)S0[13], (_Float16)S0[14], (_Float16)S0[15] };
      else if (c == 2) ph = (v8h){ (_Float16)S1[0], (_Float16)S1[1], (_Float16)S1[2], (_Float16)S1[3],
                                   (_Float16)S1[4], (_Float16)S1[5], (_Float16)S1[6], (_Float16)S1[7] };
      else             ph = (v8h){ (_Float16)S1[8], (_Float16)S1[9], (_Float16)S1[10], (_Float16)S1[11],
                                   (_Float16)S1[12], (_Float16)S1[13], (_Float16)S1[14], (_Float16)S1[15] };
      v8h vf0 = *(const v8h*)&Vb[(l31) * 72 + c * 16 + h8];
      v8h vf1 = *(const v8h*)&Vb[(32 + l31) * 72 + c * 16 + h8];
      O0 = __builtin_amdgcn_mfma_f32_32x32x16_f16(vf0, ph, O0, 0, 0, 0);
      O1 = __builtin_amdgcn_mfma_f32_32x32x16_f16(vf1, ph, O1, 0, 0, 0);
    }
    __builtin_amdgcn_s_setprio(0);
  }
  // lanes l and l+32 hold the same query column (halves of the key rows)
  l_ += __shfl_xor(l_, 32, 64);
  const float inv = 1.f / l_;
  const int b = bh >> 4, hh = bh & 15;
  const int q = qt0 + w * 32 + l31;
  _Float16* cbase = ctx + ((size_t)q * 2 + b) * 1024 + hh * 64 + (h8 >> 1);  // +4*hi
#pragma unroll
  for (int rq = 0; rq < 4; ++rq) {
    v4h o0 = { (_Float16)(O0[rq * 4 + 0] * inv), (_Float16)(O0[rq * 4 + 1] * inv),
               (_Float16)(O0[rq * 4 + 2] * inv), (_Float16)(O0[rq * 4 + 3] * inv) };
    *(v4h*)(cbase + rq * 8) = o0;
    v4h o1 = { (_Float16)(O1[rq * 4 + 0] * inv), (_Float16)(O1[rq * 4 + 1] * inv),
               (_Float16)(O1[rq * 4 + 2] * inv), (_Float16)(O1[rq * 4 + 3] * inv) };
    *(v4h*)(cbase + 32 + rq * 8) = o1;
  }
}

extern "C" void kernel_launch(void* const* d_in, const int* in_sizes, int n_in,
                              void* d_out, int out_size, void* d_ws, size_t ws_size,
                              hipStream_t stream) {
  (void)in_sizes; (void)n_in; (void)out_size; (void)ws_size;
  const float* query = (const float*)d_in[0];
  const float* key_  = (const float*)d_in[1];
  const float* value = (const float*)d_in[2];
  const float* wq = (const float*)d_in[3];
  const float* bq = (const float*)d_in[4];
  const float* wk = (const float*)d_in[5];
  const float* bk = (const float*)d_in[6];
  const float* wv = (const float*)d_in[7];
  const float* bv = (const float*)d_in[8];
  const float* wo = (const float*)d_in[9];
  const float* bo = (const float*)d_in[10];
  const float* wte = (const float*)d_in[11];
  const float* w1 = (const float*)d_in[12];
  const float* b1 = (const float*)d_in[13];
  const float* w2 = (const float*)d_in[14];
  const float* b2 = (const float*)d_in[15];
  const int* lang = (const int*)d_in[16];
  float* out = (float*)d_out;

  const size_t NTB = (size_t)T_SEQ * BATCH * DIM;   // 4194304
  const size_t DD  = (size_t)DIM * DIM;             // 1048576
  const size_t KVN = (size_t)BATCH * NH * TKP * HD; // 4325376
  _Float16* xq  = (_Float16*)d_ws;
  _Float16* xk  = xq + NTB;
  _Float16* xv  = xk + NTB;
  _Float16* wqb = xv + NTB;
  _Float16* wkb = wqb + DD;
  _Float16* wvb = wkb + DD;
  _Float16* wob = wvb + DD;
  _Float16* qbuf = wob + DD;
  _Float16* kbuf = qbuf + NTB;
  _Float16* vbuf = kbuf + KVN;
  float* hbuf = (float*)(vbuf + KVN);
  _Float16* ctxb = xq;   // alias: xq is dead after the QKV projections

  cvt_all<<<16384, 256, 0, stream>>>((const float4*)query, (const float4*)key_,
                                     (const float4*)value, (const float4*)wq,
                                     (const float4*)wk, (const float4*)wv, (const float4*)wo,
                                     (v4h*)xq, (v4h*)xk, (v4h*)xv, (v4h*)wqb,
                                     (v4h*)wkb, (v4h*)wvb, (v4h*)wob);
  prefix_pad_k<<<432, 256, 0, stream>>>(wte, w1, b1, lang, hbuf, kbuf, vbuf);
  prefix_kv_k<<<1024, 256, 0, stream>>>(w2, b2, hbuf, lang, kbuf, vbuf);
  gemm_bt_k<<<dim3(32, 8, 3), 256, 0, stream>>>(xq, xk, xv, wqb, wkb, wvb, bq, bk, bv,
                                                qbuf, kbuf, vbuf, nullptr, 0);
  attn_k<<<dim3(32, 16), 256, 0, stream>>>(qbuf, kbuf, vbuf, ctxb);
  gemm_bt_k<<<dim3(32, 8, 1), 256, 0, stream>>>(ctxb, ctxb, ctxb, wob, wob, wob, bo, bo, bo,
                                                qbuf, kbuf, vbuf, out, 3);
}

// Round 8
// 272.995 us; speedup vs baseline: 1.1724x; 1.0126x over previous
//
#include <hip/hip_runtime.h>
#include <stdint.h>

// Problem constants
#define T_SEQ 2048
#define BATCH 2
#define DIM   1024
#define NH    16
#define HD    64
#define TKP   2112   // padded key rows: keys 0..2047, prefix at 2048, zeros 2049..2111

typedef _Float16 v8h __attribute__((ext_vector_type(8)));
typedef _Float16 v4h __attribute__((ext_vector_type(4)));
typedef __fp16   pkh2 __attribute__((ext_vector_type(2)));   // cvt_pkrtz result type
typedef float    f32x4 __attribute__((ext_vector_type(4)));
typedef float    f32x16 __attribute__((ext_vector_type(16)));

// async global->LDS, 16B per lane; LDS dst must be wave-uniform base (lane*16 auto)
__device__ __forceinline__ void gload16(const _Float16* g, _Float16* l) {
  __builtin_amdgcn_global_load_lds(
      (__attribute__((address_space(1))) unsigned int*)g,
      (__attribute__((address_space(3))) unsigned int*)l, 16, 0, 0);
}

// ---------------- fused f32 -> f16 convert (q,k,v,wq,wk,wv,wo in one launch) ------
__global__ void cvt_all(const float4* __restrict__ s0, const float4* __restrict__ s1,
                        const float4* __restrict__ s2, const float4* __restrict__ s3,
                        const float4* __restrict__ s4, const float4* __restrict__ s5,
                        const float4* __restrict__ s6,
                        v4h* __restrict__ d0, v4h* __restrict__ d1, v4h* __restrict__ d2,
                        v4h* __restrict__ d3, v4h* __restrict__ d4, v4h* __restrict__ d5,
                        v4h* __restrict__ d6) {
  const int NTB4 = 1048576, DD4 = 262144;      // float4 counts
  int i = blockIdx.x * 256 + threadIdx.x;      // 0..4194303
  const float4* s; v4h* d; int off;
  if (i < 3 * NTB4) {
    int t = i / NTB4; off = i - t * NTB4;
    s = t == 0 ? s0 : t == 1 ? s1 : s2;
    d = t == 0 ? d0 : t == 1 ? d1 : d2;
  } else {
    int j = i - 3 * NTB4;
    int t = j / DD4; off = j - t * DD4;
    s = t == 0 ? s3 : t == 1 ? s4 : t == 2 ? s5 : s6;
    d = t == 0 ? d3 : t == 1 ? d4 : t == 2 ? d5 : d6;
  }
  float4 v = s[off];
  v4h o = { (_Float16)v.x, (_Float16)v.y, (_Float16)v.z, (_Float16)v.w };
  d[off] = o;
}

// ---------------- prefix MLP stage 1 + K/V pad zeroing (merged: one launch) ------
__global__ void prefix_pad_k(const float* __restrict__ wte, const float* __restrict__ w1,
                             const float* __restrict__ b1, const int* __restrict__ lang,
                             float* __restrict__ hbuf,
                             _Float16* __restrict__ kb, _Float16* __restrict__ vb) {
  if (blockIdx.x >= 400) {
    // pad part: zero key rows 2048..2111 / V cols 2048..2111 (prefix_kv_k then
    // overwrites slot 2048). Contiguous 16B stores.
    int bh = blockIdx.x - 400;
    v8h z = {};
    _Float16* kp = kb + ((size_t)bh * TKP + 2048) * 64;    // 64 rows x 64 = contiguous
    for (int i = threadIdx.x; i < 512; i += 256) *(v8h*)&kp[i * 8] = z;
    for (int i = threadIdx.x; i < 512; i += 256) {         // 64 hd-rows x 64 t, 8 segs
      int c = i >> 3, seg = i & 7;
      *(v8h*)&vb[((size_t)bh * 64 + c) * TKP + 2048 + seg * 8] = z;
    }
    return;
  }
  int wid = blockIdx.x * 4 + (threadIdx.x >> 6);   // 0..1599 = b*800+j
  int lane = threadIdx.x & 63;
  int b = wid / 800, j = wid - b * 800;
  int c = lang[b];
  const float* wr = w1 + ((size_t)c * 800 + j) * 1024;
  const float* em = wte + (size_t)c * 1024;
  float s = 0.f;
  for (int d = lane; d < 1024; d += 64) s += wr[d] * em[d];
  for (int off = 32; off > 0; off >>= 1) s += __shfl_down(s, off, 64);
  if (lane == 0) hbuf[wid] = tanhf(s + b1[c * 800 + j]);
}

// kv[b,e]: e<1024 -> prefix K (key slot 2048), else prefix V (col slot 2048)
__global__ void prefix_kv_k(const float* __restrict__ w2, const float* __restrict__ b2,
                            const float* __restrict__ hbuf, const int* __restrict__ lang,
                            _Float16* __restrict__ kb, _Float16* __restrict__ vb) {
  int wid = blockIdx.x * 4 + (threadIdx.x >> 6);   // 0..4095 = b*2048+e
  int lane = threadIdx.x & 63;
  int b = wid >> 11, e = wid & 2047;
  int c = lang[b];
  const float* wr = w2 + ((size_t)c * 2048 + e) * 800;
  const float* hb = hbuf + b * 800;
  float s = 0.f;
  for (int j = lane; j < 800; j += 64) s += wr[j] * hb[j];
  for (int off = 32; off > 0; off >>= 1) s += __shfl_down(s, off, 64);
  if (lane == 0) {
    float val = s + b2[c * 2048 + e];
    if (e < 1024) {
      int h = e >> 6, hd = e & 63;
      kb[((size_t)(b * 16 + h) * TKP + 2048) * 64 + hd] = (_Float16)val;
    } else {
      int d = e - 1024;
      int h = d >> 6, hd = d & 63;
      vb[((size_t)(b * 16 + h) * 64 + hd) * TKP + 2048] = (_Float16)val;
    }
  }
}

// ---------------- gemm_bt: Out[r,e] = sum_d A[r,d]*W[e,d] + bias[e] ----------------
// 128x128 tile, BK=64, 4 waves 2x2, 16x16x32 f16 MFMA.
// v7 K-loop: double-buffered LDS (64KB) + issue-ahead staging, raw s_barrier +
// counted "s_waitcnt vmcnt(8)" (never 0 in-loop) so the next step's 8 loads stay
// in flight under compute; T2 XOR-swizzle (pre-swizzled GLOBAL source segment,
// linear LDS dest for global_load_lds; reads use slot^(l15&7)).
// mode 0: q (*0.125*log2e -> [B,H,T,hd]); 1: k (-> [B,H,t,hd], prefix at 2048);
// mode 2: v transposed (-> [B,H,hd,t]); 3: fp32 out (d_out [T,B,D], direct stores)
__global__ __launch_bounds__(256) void gemm_bt_k(
    const _Float16* __restrict__ A0, const _Float16* __restrict__ A1, const _Float16* __restrict__ A2,
    const _Float16* __restrict__ W0, const _Float16* __restrict__ W1, const _Float16* __restrict__ W2,
    const float* __restrict__ bs0, const float* __restrict__ bs1, const float* __restrict__ bs2,
    _Float16* __restrict__ qb, _Float16* __restrict__ kb, _Float16* __restrict__ vb,
    float* __restrict__ fout, int mode_base)
{
  __shared__ __align__(16) _Float16 smem[2][128 * 64 * 2];   // [buf][As|Bs]
  const int mode = mode_base + blockIdx.z;
  const _Float16* A = (mode == 1) ? A1 : (mode == 2) ? A2 : A0;
  const _Float16* W = (mode == 1) ? W1 : (mode == 2) ? W2 : W0;
  const float* bias = (mode == 1) ? bs1 : (mode == 2) ? bs2 : bs0;
  const int tid = threadIdx.x, w = tid >> 6, lane = tid & 63;
  const int quad = lane >> 4, l15 = lane & 15;
  const int r0 = blockIdx.x * 128, c0 = blockIdx.y * 128;
  const int wm = w >> 1, wn = w & 1;
  const int srow = lane >> 3, sseg = lane & 7;   // srow 0..7, sseg 0..7
  const int sw_seg = sseg ^ srow;                // pre-swizzled global segment
  const int rsw = l15 & 7;                       // read-side row-XOR
  f32x4 acc[4][4] = {};

  // stage K-step tile k0 into buffer p (8 gload_lds per wave)
  auto stage = [&](int k0, int p) {
    _Float16* As = smem[p];
    _Float16* Bs = smem[p] + 8192;
#pragma unroll
    for (int i = 0; i < 4; ++i) {
      int rowb = w * 32 + i * 8;
      gload16(A + (size_t)(r0 + rowb + srow) * 1024 + k0 + sw_seg * 8, &As[rowb * 64]);
      gload16(W + (size_t)(c0 + rowb + srow) * 1024 + k0 + sw_seg * 8, &Bs[rowb * 64]);
    }
  };

  stage(0, 0);                                   // prologue: 8 outstanding
  for (int t = 0; t < 16; ++t) {
    if (t < 15) {
      stage((t + 1) << 6, (t + 1) & 1);          // 16 outstanding
      asm volatile("s_waitcnt vmcnt(8)" ::: "memory");   // wait ONLY step t's 8
    } else {
      asm volatile("s_waitcnt vmcnt(0)" ::: "memory");
    }
    __builtin_amdgcn_s_barrier();                // all waves' buf[t] complete
    __builtin_amdgcn_sched_barrier(0);
    const _Float16* As = smem[t & 1];
    const _Float16* Bs = smem[t & 1] + 8192;
#pragma unroll
    for (int ks = 0; ks < 2; ++ks) {
      v8h af[4], bfr[4];
#pragma unroll
      for (int mt = 0; mt < 4; ++mt)
        af[mt] = *(const v8h*)&As[(wm * 64 + mt * 16 + l15) * 64 + (((ks * 4 + quad) ^ rsw) * 8)];
#pragma unroll
      for (int nt = 0; nt < 4; ++nt)
        bfr[nt] = *(const v8h*)&Bs[(wn * 64 + nt * 16 + l15) * 64 + (((ks * 4 + quad) ^ rsw) * 8)];
#pragma unroll
      for (int mt = 0; mt < 4; ++mt)
#pragma unroll
        for (int nt = 0; nt < 4; ++nt)
          acc[mt][nt] = __builtin_amdgcn_mfma_f32_16x16x32_f16(af[mt], bfr[nt], acc[mt][nt], 0, 0, 0);
    }
    __builtin_amdgcn_sched_barrier(0);
    __builtin_amdgcn_s_barrier();                // reads of buf[t] done before its next DMA
  }
  // ---- epilogue; C/D layout: col = lane&15, row = quad*4 + reg ----
  if (mode == 3) {
    // fp32 direct: 16 l15-lanes x 4B = one full 64B line per quad. Already ideal.
    for (int nt = 0; nt < 4; ++nt) {
      int e = c0 + wn * 64 + nt * 16 + l15;
      float be = bias[e];
      for (int mt = 0; mt < 4; ++mt) {
        int rb = r0 + wm * 64 + mt * 16 + quad * 4;
        for (int reg = 0; reg < 4; ++reg)
          fout[(size_t)(rb + reg) * 1024 + e] = acc[mt][nt][reg] + be;
      }
    }
    return;
  }
  _Float16* st = &smem[0][0] + w * 4096;         // wave-private stage (8192 B)
  // mode 0: fold softmax's log2(e) into the Q scale so attn can use raw v_exp_f32
  const float qscale = (mode == 0) ? 0.125f * 1.44269504088896341f : 1.0f;
  for (int p = 0; p < 2; ++p) {                  // pass = half of the e-range (32 cols)
    __syncthreads();
    for (int ntl = 0; ntl < 2; ++ntl) {
      int nt = p * 2 + ntl;
      int e = c0 + wn * 64 + nt * 16 + l15;
      float be = bias[e];
      for (int mt = 0; mt < 4; ++mt)
        for (int reg = 0; reg < 4; ++reg) {
          float val = (acc[mt][nt][reg] + be) * qscale;
          int rl = mt * 16 + quad * 4 + reg;     // 0..63 local row
          if (mode != 2) st[rl * 40 + ntl * 16 + l15] = (_Float16)val;       // stride 40: 80B, 16B-mult
          else st[(ntl * 16 + l15) * 72 + (rl & 1) * 32 + (rl >> 1)] = (_Float16)val;  // stride 72: 144B
        }
    }
    __syncthreads();
    if (mode != 2) {
      // st[row r (64)][e (32), stride 40]; 4-lane groups write full 64B lines
      for (int it = 0; it < 4; ++it) {
        int chunk = it * 64 + lane;              // 0..255
        int rr = chunk >> 2, seg = chunk & 3;
        v8h val = *(const v8h*)&st[rr * 40 + seg * 8];
        int r = r0 + wm * 64 + rr, b = r & 1, t = r >> 1;
        int e0 = c0 + wn * 64 + p * 32 + seg * 8;
        int h = e0 >> 6, hd0 = e0 & 63;
        if (mode == 0) *(v8h*)&qb[((size_t)(b * 16 + h) * 2048 + t) * 64 + hd0] = val;
        else           *(v8h*)&kb[((size_t)(b * 16 + h) * TKP + t) * 64 + hd0] = val;
      }
    } else {
      // st[e (32), stride 72][b(2)*32 + t(32)]; 4-lane groups write full 64B lines
      for (int it = 0; it < 4; ++it) {
        int chunk = it * 64 + lane;              // 0..255
        int el = chunk >> 3, b = (chunk >> 2) & 1, qs = chunk & 3;
        v8h val = *(const v8h*)&st[el * 72 + b * 32 + qs * 8];
        int e = c0 + wn * 64 + p * 32 + el;
        int h = e >> 6, hd = e & 63;
        int t0 = ((r0 + wm * 64) >> 1) + qs * 8;
        *(v8h*)&vb[((size_t)(b * 16 + h) * 64 + hd) * TKP + t0] = val;
      }
    }
  }
}

// ---------------- flash attention (v8b: VALU-cut; pkrtz type fixed) ---------------
// v6 counters: MfmaUtil 25, VALUBusy 48, conflicts 0 -> VALU is the top pipe.
// Per-iter VALU was ~116: 32 exp2 + 32 SERIAL fp-add chain (denominator) + ~48
// scalar cvt/pack for the P frag. v8 cuts:
//  - v_cvt_pkrtz_f16_f32 (builtin returns __fp16x2 -> union member is __fp16-typed):
//    exp2 fused straight into 16 pack ops.
//  - softmax denominator via MFMA: lacc = mfma(ones, ph, lacc) per 16-key chunk
//    (A=ones -> every D row = column sum; B fragment spans both lane halves so
//    lacc[0] is the FULL denominator -> end-of-loop shfl_xor also gone).
// Structure unchanged otherwise: 32x32 MFMA, no-exchange PV (sigma-staged V),
// key(c,hi,j) = c*16 + (j&3) + 8*(j>>2) + 4*hi, LDS 36.9KB dbuf.
__global__ __launch_bounds__(256) void attn_k(
    const _Float16* __restrict__ qb, const _Float16* __restrict__ kb,
    const _Float16* __restrict__ vb, _Float16* __restrict__ ctx)
{
  __shared__ __align__(16) _Float16 Ks[2][64 * 72];
  __shared__ __align__(16) _Float16 Vs[2][64 * 72];
  const int bh = blockIdx.x;
  const int qt0 = blockIdx.y * 128;
  const int tid = threadIdx.x, w = tid >> 6, lane = tid & 63;
  const int l31 = lane & 31, h8 = (lane >> 5) * 8;
  // loop-invariant Q fragments (B-operand, 32x32x16): n = l31 (query), k = t*16+h8+j
  v8h qf[4];
#pragma unroll
  for (int t = 0; t < 4; ++t)
    qf[t] = *(const v8h*)(qb + ((size_t)bh * 2048 + qt0 + w * 32 + l31) * 64 + t * 16 + h8);
  // staging coords: row = tid>>3 (0..31, +32 for second half), seg = tid&7
  const int sr = tid >> 3, sseg = tid & 7;
  const _Float16* kptr = kb + (size_t)bh * TKP * 64 + sr * 64 + sseg * 8;
  const _Float16* vptr = vb + (size_t)bh * 64 * TKP + (size_t)sr * TKP + sseg * 8;
  int4 kp0 = *(const int4*)kptr, kp1 = *(const int4*)(kptr + 2048);
  int4 vp0 = *(const int4*)vptr, vp1 = *(const int4*)(vptr + 32 * TKP);
  kptr += 4096; vptr += 64;
  // sigma staging byte-col of this thread's first 4-key group within its V row:
  // keys sseg*8..+3 -> chunk c=sseg>>1, half (sseg&1): col = c*32 + (sseg&1)*8;
  // keys sseg*8+4..+7 -> col + 16.
  const int vcb = (sseg >> 1) * 32 + (sseg & 1) * 8;
  const v8h vones = { (_Float16)1.f, (_Float16)1.f, (_Float16)1.f, (_Float16)1.f,
                      (_Float16)1.f, (_Float16)1.f, (_Float16)1.f, (_Float16)1.f };
  f32x16 O0 = {}, O1 = {}, lacc = {};
  for (int kc = 0; kc < 33; ++kc) {
    _Float16* Kb = Ks[kc & 1];
    _Float16* Vb = Vs[kc & 1];
    // write chunk kc (in regs) to this iter's buffer; parity keeps it race-free
    // vs. waves still computing kc-1 on the other buffer.
    *(int4*)&Kb[sr * 72 + sseg * 8] = kp0;
    *(int4*)&Kb[(sr + 32) * 72 + sseg * 8] = kp1;
    {
      char* vr0 = (char*)&Vb[sr * 72];
      char* vr1 = (char*)&Vb[(sr + 32) * 72];
      *(int2*)(vr0 + vcb)      = *(int2*)&vp0;
      *(int2*)(vr0 + vcb + 16) = *((int2*)&vp0 + 1);
      *(int2*)(vr1 + vcb)      = *(int2*)&vp1;
      *(int2*)(vr1 + vcb + 16) = *((int2*)&vp1 + 1);
    }
    __syncthreads();
    if (kc < 32) {                                 // prefetch next chunk; lands during compute
      kp0 = *(const int4*)kptr; kp1 = *(const int4*)(kptr + 2048);
      vp0 = *(const int4*)vptr; vp1 = *(const int4*)(vptr + 32 * TKP);
      kptr += 4096; vptr += 64;
    }
    // S^T = K(64keys x 64d) . Q^T: two 32x32 key tiles, 4 k-steps of 16
    f32x16 S0 = {}, S1 = {};
    __builtin_amdgcn_s_setprio(1);
#pragma unroll
    for (int t = 0; t < 4; ++t) {
      v8h kf0 = *(const v8h*)&Kb[(l31) * 72 + t * 16 + h8];
      v8h kf1 = *(const v8h*)&Kb[(32 + l31) * 72 + t * 16 + h8];
      S0 = __builtin_amdgcn_mfma_f32_32x32x16_f16(kf0, qf[t], S0, 0, 0, 0);
      S1 = __builtin_amdgcn_mfma_f32_32x32x16_f16(kf1, qf[t], S1, 0, 0, 0);
    }
    __builtin_amdgcn_s_setprio(0);
    if (kc == 32) {             // local key 0 = prefix (valid, tile0/hi=0/reg0); rest pad
#pragma unroll
      for (int r = 0; r < 16; ++r) {
        if (r > 0) S0[r] = -1e30f;
        S1[r] = -1e30f;
      }
      if (lane >= 32) S0[0] = -1e30f;
    }
    // P = exp2(S) (log2e folded into Q projection), packed with v_cvt_pkrtz.
    // O^T += V^T . P (B-fragment = lane's OWN exp'd S regs, sigma-staged V);
    // lacc += ones . P accumulates the softmax denominator per query column.
    __builtin_amdgcn_s_setprio(1);
#pragma unroll
    for (int c = 0; c < 4; ++c) {
      union { v8h v; pkh2 p[4]; } f;
      if (c == 0) {
        f.p[0] = __builtin_amdgcn_cvt_pkrtz(__builtin_amdgcn_exp2f(S0[0]), __builtin_amdgcn_exp2f(S0[1]));
        f.p[1] = __builtin_amdgcn_cvt_pkrtz(__builtin_amdgcn_exp2f(S0[2]), __builtin_amdgcn_exp2f(S0[3]));
        f.p[2] = __builtin_amdgcn_cvt_pkrtz(__builtin_amdgcn_exp2f(S0[4]), __builtin_amdgcn_exp2f(S0[5]));
        f.p[3] = __builtin_amdgcn_cvt_pkrtz(__builtin_amdgcn_exp2f(S0[6]), __builtin_amdgcn_exp2f(S0[7]));
      } else if (c == 1) {
        f.p[0] = __builtin_amdgcn_cvt_pkrtz(__builtin_amdgcn_exp2f(S0[8]),  __builtin_amdgcn_exp2f(S0[9]));
        f.p[1] = __builtin_amdgcn_cvt_pkrtz(__builtin_amdgcn_exp2f(S0[10]), __builtin_amdgcn_exp2f(S0[11]));
        f.p[2] = __builtin_amdgcn_cvt_pkrtz(__builtin_amdgcn_exp2f(S0[12]), __builtin_amdgcn_exp2f(S0[13]));
        f.p[3] = __builtin_amdgcn_cvt_pkrtz(__builtin_amdgcn_exp2f(S0[14]), __builtin_amdgcn_exp2f(S0[15]));
      } else if (c == 2) {
        f.p[0] = __builtin_amdgcn_cvt_pkrtz(__builtin_amdgcn_exp2f(S1[0]), __builtin_amdgcn_exp2f(S1[1]));
        f.p[1] = __builtin_amdgcn_cvt_pkrtz(__builtin_amdgcn_exp2f(S1[2]), __builtin_amdgcn_exp2f(S1[3]));
        f.p[2] = __builtin_amdgcn_cvt_pkrtz(__builtin_amdgcn_exp2f(S1[4]), __builtin_amdgcn_exp2f(S1[5]));
        f.p[3] = __builtin_amdgcn_cvt_pkrtz(__builtin_amdgcn_exp2f(S1[6]), __builtin_amdgcn_exp2f(S1[7]));
      } else {
        f.p[0] = __builtin_amdgcn_cvt_pkrtz(__builtin_amdgcn_exp2f(S1[8]),  __builtin_amdgcn_exp2f(S1[9]));
        f.p[1] = __builtin_amdgcn_cvt_pkrtz(__builtin_amdgcn_exp2f(S1[10]), __builtin_amdgcn_exp2f(S1[11]));
        f.p[2] = __builtin_amdgcn_cvt_pkrtz(__builtin_amdgcn_exp2f(S1[12]), __builtin_amdgcn_exp2f(S1[13]));
        f.p[3] = __builtin_amdgcn_cvt_pkrtz(__builtin_amdgcn_exp2f(S1[14]), __builtin_amdgcn_exp2f(S1[15]));
      }
      v8h vf0 = *(const v8h*)&Vb[(l31) * 72 + c * 16 + h8];
      v8h vf1 = *(const v8h*)&Vb[(32 + l31) * 72 + c * 16 + h8];
      O0 = __builtin_amdgcn_mfma_f32_32x32x16_f16(vf0, f.v, O0, 0, 0, 0);
      O1 = __builtin_amdgcn_mfma_f32_32x32x16_f16(vf1, f.v, O1, 0, 0, 0);
      lacc = __builtin_amdgcn_mfma_f32_32x32x16_f16(vones, f.v, lacc, 0, 0, 0);
    }
    __builtin_amdgcn_s_setprio(0);
  }
  // lacc rows all equal the per-query-column denominator (summed over ALL keys,
  // both lane halves included via the B fragment) -> no cross-lane reduce.
  const float inv = 1.f / lacc[0];
  const int b = bh >> 4, hh = bh & 15;
  const int q = qt0 + w * 32 + l31;
  _Float16* cbase = ctx + ((size_t)q * 2 + b) * 1024 + hh * 64 + (h8 >> 1);  // +4*hi
#pragma unroll
  for (int rq = 0; rq < 4; ++rq) {
    v4h o0 = { (_Float16)(O0[rq * 4 + 0] * inv), (_Float16)(O0[rq * 4 + 1] * inv),
               (_Float16)(O0[rq * 4 + 2] * inv), (_Float16)(O0[rq * 4 + 3] * inv) };
    *(v4h*)(cbase + rq * 8) = o0;
    v4h o1 = { (_Float16)(O1[rq * 4 + 0] * inv), (_Float16)(O1[rq * 4 + 1] * inv),
               (_Float16)(O1[rq * 4 + 2] * inv), (_Float16)(O1[rq * 4 + 3] * inv) };
    *(v4h*)(cbase + 32 + rq * 8) = o1;
  }
}

extern "C" void kernel_launch(void* const* d_in, const int* in_sizes, int n_in,
                              void* d_out, int out_size, void* d_ws, size_t ws_size,
                              hipStream_t stream) {
  (void)in_sizes; (void)n_in; (void)out_size; (void)ws_size;
  const float* query = (const float*)d_in[0];
  const float* key_  = (const float*)d_in[1];
  const float* value = (const float*)d_in[2];
  const float* wq = (const float*)d_in[3];
  const float* bq = (const float*)d_in[4];
  const float* wk = (const float*)d_in[5];
  const float* bk = (const float*)d_in[6];
  const float* wv = (const float*)d_in[7];
  const float* bv = (const float*)d_in[8];
  const float* wo = (const float*)d_in[9];
  const float* bo = (const float*)d_in[10];
  const float* wte = (const float*)d_in[11];
  const float* w1 = (const float*)d_in[12];
  const float* b1 = (const float*)d_in[13];
  const float* w2 = (const float*)d_in[14];
  const float* b2 = (const float*)d_in[15];
  const int* lang = (const int*)d_in[16];
  float* out = (float*)d_out;

  const size_t NTB = (size_t)T_SEQ * BATCH * DIM;   // 4194304
  const size_t DD  = (size_t)DIM * DIM;             // 1048576
  const size_t KVN = (size_t)BATCH * NH * TKP * HD; // 4325376
  _Float16* xq  = (_Float16*)d_ws;
  _Float16* xk  = xq + NTB;
  _Float16* xv  = xk + NTB;
  _Float16* wqb = xv + NTB;
  _Float16* wkb = wqb + DD;
  _Float16* wvb = wkb + DD;
  _Float16* wob = wvb + DD;
  _Float16* qbuf = wob + DD;
  _Float16* kbuf = qbuf + NTB;
  _Float16* vbuf = kbuf + KVN;
  float* hbuf = (float*)(vbuf + KVN);
  _Float16* ctxb = xq;   // alias: xq is dead after the QKV projections

  cvt_all<<<16384, 256, 0, stream>>>((const float4*)query, (const float4*)key_,
                                     (const float4*)value, (const float4*)wq,
                                     (const float4*)wk, (const float4*)wv, (const float4*)wo,
                                     (v4h*)xq, (v4h*)xk, (v4h*)xv, (v4h*)wqb,
                                     (v4h*)wkb, (v4h*)wvb, (v4h*)wob);
  prefix_pad_k<<<432, 256, 0, stream>>>(wte, w1, b1, lang, hbuf, kbuf, vbuf);
  prefix_kv_k<<<1024, 256, 0, stream>>>(w2, b2, hbuf, lang, kbuf, vbuf);
  gemm_bt_k<<<dim3(32, 8, 3), 256, 0, stream>>>(xq, xk, xv, wqb, wkb, wvb, bq, bk, bv,
                                                qbuf, kbuf, vbuf, nullptr, 0);
  attn_k<<<dim3(32, 16), 256, 0, stream>>>(qbuf, kbuf, vbuf, ctxb);
  gemm_bt_k<<<dim3(32, 8, 1), 256, 0, stream>>>(ctxb, ctxb, ctxb, wob, wob, wob, bo, bo, bo,
                                                qbuf, kbuf, vbuf, out, 3);
}